// Round 14
// baseline (1144.743 us; speedup 1.0000x reference)
//
#include <hip/hip_runtime.h>
#include <math.h>

#define HID 128
#define NEXP 8
#define NGRAPH 64
#define NREP 8         // pool replicas (atomic-contention spreading)
#define NPS 8          // nodes per slot in k_pz

__device__ inline float atomAddF(float* p, float v) { return unsafeAtomicAdd(p, v); }

// ---------------- init: zero cnt/agg4/zacc/pool/pcnt, C = W2@Wlin, bb2 ---------
__global__ void k_init0(int* __restrict__ cnt, float4* __restrict__ agg4,
                        float* __restrict__ zacc, float* __restrict__ pool,
                        float* __restrict__ pcnt, const float* __restrict__ W2,
                        const float* __restrict__ Wlin, const float* __restrict__ b2,
                        float* __restrict__ C, float* __restrict__ bb2, int n) {
    int i = blockIdx.x * 256 + threadIdx.x;
    if (i < n * NEXP) zacc[i] = 0.0f;
    if (i < n) {
        cnt[i] = 0;
        agg4[i] = make_float4(0.0f, 0.0f, 0.0f, 0.0f);
    }
    if (i < NREP * NGRAPH * NEXP) pool[i] = 0.0f;
    if (i < NREP * NGRAPH) pcnt[i] = 0.0f;
    if (i < HID * NEXP) {                    // C[k][j] = sum_m W2[k][m]*Wlin[m][j]
        int k = i >> 3, j = i & 7;
        float s = 0.0f;
        for (int m = 0; m < HID; m++) s += W2[k * HID + m] * Wlin[m * NEXP + j];
        C[i] = s;
    } else if (i - HID * NEXP < NEXP) {      // bb2[j] = sum_m b2[m]*Wlin[m][j]
        int bi = i - HID * NEXP;
        float s = 0.0f;
        for (int m = 0; m < HID; m++) s += b2[m] * Wlin[m * NEXP + bi];
        bb2[bi] = s;
    }
}

// ---------------- degree: cnt[dst]++ -------------------------------------------
__global__ void k_deg(const int* __restrict__ dst, int* __restrict__ cnt, int e) {
    int stride = gridDim.x * 256;
    for (int i = blockIdx.x * 256 + threadIdx.x; i < e; i += stride)
        atomicAdd(&cnt[dst[i]], 1);
}

// ---------------- per-node: dinv + scaled 4-dim features -----------------------
__global__ void k_dx(const float* __restrict__ an, const float* __restrict__ pos,
                     const int* __restrict__ cnt, float* __restrict__ dinv,
                     float4* __restrict__ xs, int n) {
    int i = blockIdx.x * 256 + threadIdx.x;
    if (i >= n) return;
    float di = rsqrtf((float)cnt[i] + 1.0f);   // +1 = self-loop
    dinv[i] = di;
    xs[i] = make_float4(an[i] * di, pos[3 * i] * di,
                        pos[3 * i + 1] * di, pos[3 * i + 2] * di);
}

// ---------------- layer-1 edge scatter: agg4[dst] += xs[src] -------------------
__global__ void k_s1(const int* __restrict__ src, const int* __restrict__ dst,
                     const float4* __restrict__ xs, float* __restrict__ agg4f, int e) {
    int stride = gridDim.x * 256;
    for (int i = blockIdx.x * 256 + threadIdx.x; i < e; i += stride) {
        int s = src[i], d = dst[i];
        float4 v = xs[s];
        float* ap = agg4f + (size_t)d * 4;
        atomAddF(ap + 0, v.x);
        atomAddF(ap + 1, v.y);
        atomAddF(ap + 2, v.z);
        atomAddF(ap + 3, v.w);
    }
}

// ---------------- fused layer-1 dense + z projection (fp32 z) ------------------
// one thread per node; weight indices wave-uniform -> scalar loads.
__global__ void k_hz1(const float4* __restrict__ xs, const float4* __restrict__ agg4,
                      const float* __restrict__ dinv, const float* __restrict__ W1,
                      const float* __restrict__ b1, const float* __restrict__ C,
                      float4* __restrict__ z, int n) {
    int i = blockIdx.x * 256 + threadIdx.x;
    if (i >= n) return;
    float4 self = xs[i], nb = agg4[i];
    float4 a = make_float4(self.x + nb.x, self.y + nb.y,
                           self.z + nb.z, self.w + nb.w);
    float di = dinv[i];
    float z0 = 0.f, z1 = 0.f, z2 = 0.f, z3 = 0.f,
          z4 = 0.f, z5 = 0.f, z6 = 0.f, z7 = 0.f;
#pragma unroll 4
    for (int kk = 0; kk < HID; kk++) {
        float x1k = fmaxf(di * (a.x * W1[kk] + a.y * W1[HID + kk] +
                                a.z * W1[2 * HID + kk] + a.w * W1[3 * HID + kk])
                          + b1[kk], 0.0f);
        const float* cr = C + kk * NEXP;
        z0 += x1k * cr[0]; z1 += x1k * cr[1];
        z2 += x1k * cr[2]; z3 += x1k * cr[3];
        z4 += x1k * cr[4]; z5 += x1k * cr[5];
        z6 += x1k * cr[6]; z7 += x1k * cr[7];
    }
    z[2 * (size_t)i]     = make_float4(z0 * di, z1 * di, z2 * di, z3 * di);
    z[2 * (size_t)i + 1] = make_float4(z4 * di, z5 * di, z6 * di, z7 * di);
}

// ---------------- layer-2 edge scatter: zacc[dst] += z[src] --------------------
__global__ void k_s2(const int* __restrict__ src, const int* __restrict__ dst,
                     const float4* __restrict__ z, float* __restrict__ zacc, int e) {
    int stride = gridDim.x * 256;
    for (int i = blockIdx.x * 256 + threadIdx.x; i < e; i += stride) {
        int s = src[i], d = dst[i];
        float4 a = z[2 * (size_t)s];
        float4 b = z[2 * (size_t)s + 1];
        float* ap = zacc + (size_t)d * NEXP;
        atomAddF(ap + 0, a.x); atomAddF(ap + 1, a.y);
        atomAddF(ap + 2, a.z); atomAddF(ap + 3, a.w);
        atomAddF(ap + 4, b.x); atomAddF(ap + 5, b.y);
        atomAddF(ap + 6, b.z); atomAddF(ap + 7, b.w);
    }
}

// ---------------- finalize + segment pooling -----------------------------------
// block = 32 slots x 8 lanes; slot handles NPS consecutive nodes; register
// run-accumulation by graph; flush to replicated pool via atomics.
__global__ void k_pz(const float* __restrict__ zacc, const float* __restrict__ z,
                     const float* __restrict__ dinv, const int* __restrict__ batch,
                     float* __restrict__ pool, float* __restrict__ pcnt, int n) {
    int t = threadIdx.x;
    int slot = t >> 3;          // 0..31
    int j = t & 7;
    int i0 = blockIdx.x * (32 * NPS) + slot * NPS;
    if (i0 >= n) return;
    int i1 = i0 + NPS < n ? i0 + NPS : n;
    int rep = (blockIdx.x + slot) & (NREP - 1);
    float* rp  = pool + (size_t)rep * NGRAPH * NEXP;
    float* rpc = pcnt + (size_t)rep * NGRAPH;

    int curg = -1;
    float r = 0.0f, runlen = 0.0f;
    for (int i = i0; i < i1; i++) {
        float v = dinv[i] * (zacc[(size_t)i * NEXP + j] + z[(size_t)i * NEXP + j]);
        int g = batch[i];
        if (g != curg) {                     // slot-uniform branch
            if (curg >= 0) {
                atomicAdd(&rp[curg * NEXP + j], r);
                if (j == 0) atomicAdd(&rpc[curg], runlen);
            }
            curg = g; r = v; runlen = 1.0f;
        } else { r += v; runlen += 1.0f; }
    }
    if (curg >= 0) {
        atomicAdd(&rp[curg * NEXP + j], r);
        if (j == 0) atomicAdd(&rpc[curg], runlen);
    }
}

// ---------------- replica-sum + mean + (blin + b2@Wlin) + log_softmax ----------
__global__ void k_lsm(const float* __restrict__ pool, const float* __restrict__ pcnt,
                      const float* __restrict__ blin, const float* __restrict__ bb2,
                      float* __restrict__ out) {
    int g = threadIdx.x;
    if (g >= NGRAPH) return;
    float p[NEXP];
#pragma unroll
    for (int k = 0; k < NEXP; k++) p[k] = 0.0f;
    float cg = 0.0f;
#pragma unroll
    for (int rr = 0; rr < NREP; rr++) {
#pragma unroll
        for (int k = 0; k < NEXP; k++) p[k] += pool[rr * NGRAPH * NEXP + g * NEXP + k];
        cg += pcnt[rr * NGRAPH + g];
    }
    float inv = 1.0f / fmaxf(cg, 1.0f);
    float v[NEXP], m = -1e30f;
#pragma unroll
    for (int k = 0; k < NEXP; k++) {
        v[k] = p[k] * inv + blin[k] + bb2[k];
        m = fmaxf(m, v[k]);
    }
    float s = 0.0f;
#pragma unroll
    for (int k = 0; k < NEXP; k++) s += expf(v[k] - m);
    float ls = logf(s);
#pragma unroll
    for (int k = 0; k < NEXP; k++) out[g * NEXP + k] = v[k] - m - ls;
}

extern "C" void kernel_launch(void* const* d_in, const int* in_sizes, int n_in,
                              void* d_out, int out_size, void* d_ws, size_t ws_size,
                              hipStream_t stream) {
    const float* an   = (const float*)d_in[0];
    const float* pos  = (const float*)d_in[1];
    const int*   ei   = (const int*)d_in[2];     // [2, E] flat (int32 view)
    const int*   batch= (const int*)d_in[3];
    const float* W1   = (const float*)d_in[4];
    const float* b1   = (const float*)d_in[5];
    const float* W2   = (const float*)d_in[6];
    const float* b2   = (const float*)d_in[7];
    const float* Wlin = (const float*)d_in[8];
    const float* blin = (const float*)d_in[9];
    float* out = (float*)d_out;

    const int n = in_sizes[0];
    const int e = in_sizes[2] / 2;
    const int* src = ei;
    const int* dst = ei + e;

    // workspace layout (16B-aligned buffers first)
    char* p = (char*)d_ws;
    float4* xs    = (float4*)p;       p += sizeof(float4) * (size_t)n;
    float4* agg4  = (float4*)p;       p += sizeof(float4) * (size_t)n;
    float4* z     = (float4*)p;       p += sizeof(float4) * 2 * (size_t)n;  // fp32[8]
    float*  zacc  = (float*)p;        p += sizeof(float) * (size_t)n * NEXP;
    float* C      = (float*)p;        p += sizeof(float) * HID * NEXP;
    float* bb2    = (float*)p;        p += sizeof(float) * NEXP;
    float* dinv   = (float*)p;        p += sizeof(float) * (size_t)n;
    float* pool   = (float*)p;        p += sizeof(float) * NREP * NGRAPH * NEXP;
    float* pcnt   = (float*)p;        p += sizeof(float) * NREP * NGRAPH;
    int*   cnt    = (int*)p;          p += sizeof(int) * (size_t)n;

    const int nb256 = (n + 255) / 256;
    const int EGRID = 1024;                       // edge-kernel grid (grid-stride)

    k_init0<<<(n * NEXP + 255) / 256, 256, 0, stream>>>(cnt, agg4, zacc, pool, pcnt,
                                                        W2, Wlin, b2, C, bb2, n);
    k_deg<<<EGRID, 256, 0, stream>>>(dst, cnt, e);
    k_dx<<<nb256, 256, 0, stream>>>(an, pos, cnt, dinv, xs, n);

    // layer 1: scatter xs, then fused dense + projection to fp32 z
    k_s1<<<EGRID, 256, 0, stream>>>(src, dst, xs, (float*)agg4, e);
    k_hz1<<<nb256, 256, 0, stream>>>(xs, agg4, dinv, W1, b1, C, z, n);

    // layer 2: scatter z, then finalize + pooling + log_softmax
    k_s2<<<EGRID, 256, 0, stream>>>(src, dst, z, zacc, e);
    k_pz<<<(n + 32 * NPS - 1) / (32 * NPS), 256, 0, stream>>>(zacc, (const float*)z,
                                                              dinv, batch, pool, pcnt, n);
    k_lsm<<<1, 64, 0, stream>>>(pool, pcnt, blin, bb2, out);
}

// Round 15
// 310.080 us; speedup vs baseline: 3.6918x; 3.6918x over previous
//
#include <hip/hip_runtime.h>
#include <math.h>

#define HID 128
#define NEXP 8
#define NGRAPH 64
#define EPC 1024       // edges per chunk (hist/binA blocks) - small for occupancy
#define MAXB 512       // max coarse buckets (n <= 131072)
#define NXC 8          // XCD classes (blockIdx&7 heuristic)
#define NREP 8         // pool replicas (atomic-contention spreading)
#define NPS 2          // nodes per slot in k_gz

__device__ inline unsigned short f2bf(float f) {
    unsigned u = __float_as_uint(f);
    u += 0x7FFF + ((u >> 16) & 1);          // RNE
    return (unsigned short)(u >> 16);
}
__device__ inline unsigned packbf(float lo, float hi) {
    return (unsigned)f2bf(lo) | ((unsigned)f2bf(hi) << 16);
}
__device__ inline float bf2f(unsigned short u) {
    return __uint_as_float(((unsigned)u) << 16);
}

// ---------------- init: pool/pcnt/bcnt8 zero, C = W2@Wlin, bb2 = b2@Wlin -------
__global__ void k_init0(float* __restrict__ pool, float* __restrict__ pcnt,
                        const float* __restrict__ W2, const float* __restrict__ Wlin,
                        const float* __restrict__ b2, float* __restrict__ C,
                        float* __restrict__ bb2, int* __restrict__ bcnt8) {
    int i = blockIdx.x * 256 + threadIdx.x;
    if (i < MAXB * NXC) bcnt8[i] = 0;
    if (i < NREP * NGRAPH * NEXP) pool[i] = 0.0f;
    if (i < NREP * NGRAPH) pcnt[i] = 0.0f;
    int ci = i - NREP * NGRAPH * NEXP;
    if (ci >= 0 && ci < HID * NEXP) {        // C[k][j] = sum_m W2[k][m]*Wlin[m][j]
        int k = ci >> 3, j = ci & 7;
        float s = 0.0f;
        for (int m = 0; m < HID; m++) s += W2[k * HID + m] * Wlin[m * NEXP + j];
        C[ci] = s;
    }
    int bi = ci - HID * NEXP;
    if (bi >= 0 && bi < NEXP) {              // bb2[j] = sum_m b2[m]*Wlin[m][j]
        float s = 0.0f;
        for (int m = 0; m < HID; m++) s += b2[m] * Wlin[m * NEXP + bi];
        bb2[bi] = s;
    }
}

// ---------------- pass 0: per-(bucket, xcd-class) totals -----------------------
__global__ void k_hist(const int* __restrict__ dst, int* __restrict__ bcnt8,
                       int e, int nbuck) {
    __shared__ int h[MAXB];
    int c = blockIdx.x, t = threadIdx.x;
    int x = c & (NXC - 1);
    for (int b = t; b < nbuck; b += 256) h[b] = 0;
    __syncthreads();
    int start = c * EPC;
    int end = start + EPC < e ? start + EPC : e;
    for (int i = start + t; i < end; i += 256)
        atomicAdd(&h[dst[i] >> 8], 1);
    __syncthreads();
    for (int b = t; b < nbuck; b += 256)
        if (h[b]) atomicAdd(&bcnt8[b * NXC + x], h[b]);
}

// ---------------- scan of 8*nbuck entries + cursor init (1 block, 512 thr) -----
__global__ void k_cscan(const int* __restrict__ bcnt8, int* __restrict__ boff8,
                        int* __restrict__ gcur8, int e, int m /* = 8*nbuck */) {
    __shared__ int s[512];
    int t = threadIdx.x;
    int base = t * 8;
    int v[8];
    int sum = 0;
#pragma unroll
    for (int j = 0; j < 8; j++) {
        v[j] = (base + j < m) ? bcnt8[base + j] : 0;
        sum += v[j];
    }
    s[t] = sum;
    __syncthreads();
    for (int d = 1; d < 512; d <<= 1) {
        int x = (t >= d) ? s[t - d] : 0;
        __syncthreads();
        s[t] += x;
        __syncthreads();
    }
    int run = s[t] - sum;               // exclusive
#pragma unroll
    for (int j = 0; j < 8; j++) {
        if (base + j < m) {
            boff8[base + j] = run;
            gcur8[base + j] = run;
        }
        run += v[j];
    }
    if (t == 0) boff8[m] = e;
}

// ---------------- pass A: LDS counting-sort binning, coalesced run writes ------
__global__ void __launch_bounds__(256) k_binA(
        const int* __restrict__ src, const int* __restrict__ dst,
        int* __restrict__ gcur8, unsigned* __restrict__ binned, int e, int nbuck) {
    __shared__ int h[MAXB];
    __shared__ int ssum[256];
    __shared__ int lstart[MAXB];
    __shared__ int lcur[MAXB];
    __shared__ int gbase[MAXB];
    __shared__ unsigned packed[EPC];
    __shared__ unsigned short sbkt[EPC];
    int c = blockIdx.x, t = threadIdx.x;
    int x = c & (NXC - 1);
    int start = c * EPC;
    int m = e - start < EPC ? e - start : EPC;

    int d[4], sv[4];
#pragma unroll
    for (int j = 0; j < 4; j++) {
        int idx = j * 256 + t;
        if (idx < m) { d[j] = dst[start + idx]; sv[j] = src[start + idx]; }
    }
    h[t] = 0; h[t + 256] = 0;
    __syncthreads();
#pragma unroll
    for (int j = 0; j < 4; j++)
        if (j * 256 + t < m) atomicAdd(&h[d[j] >> 8], 1);
    __syncthreads();
    // exclusive scan of 512 counters (2 per thread)
    int v0 = h[2 * t], v1 = h[2 * t + 1];
    int sum = v0 + v1;
    ssum[t] = sum;
    __syncthreads();
    for (int dd = 1; dd < 256; dd <<= 1) {
        int xx = (t >= dd) ? ssum[t - dd] : 0;
        __syncthreads();
        ssum[t] += xx;
        __syncthreads();
    }
    int ex = ssum[t] - sum;
    lstart[2 * t] = ex;     lstart[2 * t + 1] = ex + v0;
    lcur[2 * t]   = ex;     lcur[2 * t + 1]   = ex + v0;
    __syncthreads();
    // global range reservation per touched bucket
    for (int b = t; b < nbuck; b += 256)
        gbase[b] = h[b] ? atomicAdd(&gcur8[b * NXC + x], h[b]) : 0;
    // LDS sort (scatter to dense local ranks)
#pragma unroll
    for (int j = 0; j < 4; j++) {
        if (j * 256 + t < m) {
            int b = d[j] >> 8;
            int p = atomicAdd(&lcur[b], 1);
            packed[p] = ((unsigned)(d[j] & 255) << 24) | (unsigned)sv[j];
            sbkt[p] = (unsigned short)b;
        }
    }
    __syncthreads();
    // coalesced write-out: consecutive local ranks -> consecutive global slots
    for (int idx = t; idx < m; idx += 256) {
        int b = sbkt[idx];
        binned[gbase[b] + (idx - lstart[b])] = packed[idx];
    }
}

// ---------------- pass B: per-bucket fine sort + cnt/off/dinv + xs -------------
__global__ void k_binB(const unsigned* __restrict__ binned, const int* __restrict__ boff8,
                       const float* __restrict__ an, const float* __restrict__ pos,
                       int* __restrict__ cnt, int* __restrict__ off,
                       float* __restrict__ dinv, float4* __restrict__ xs,
                       int* __restrict__ eidx, int n) {
    __shared__ int h[256];
    __shared__ int sc[256];
    __shared__ int cur[256];
    int b = blockIdx.x, t = threadIdx.x;
    int s0 = boff8[b * NXC], s1 = boff8[(b + 1) * NXC];
    h[t] = 0;
    __syncthreads();
    for (int k = s0 + t; k < s1; k += 256)
        atomicAdd(&h[binned[k] >> 24], 1);
    __syncthreads();
    int v = h[t];
    sc[t] = v;
    __syncthreads();
    for (int d = 1; d < 256; d <<= 1) {
        int x = (t >= d) ? sc[t - d] : 0;
        __syncthreads();
        sc[t] += x;
        __syncthreads();
    }
    int ex = sc[t] - v;          // exclusive within bucket
    cur[t] = ex;
    int node = (b << 8) + t;
    if (node < n) {
        float di = rsqrtf((float)v + 1.0f);   // +1 = self-loop
        cnt[node]  = v;
        off[node]  = s0 + ex;
        dinv[node] = di;
        xs[node] = make_float4(an[node] * di, pos[3 * node] * di,
                               pos[3 * node + 1] * di, pos[3 * node + 2] * di);
    }
    __syncthreads();
    for (int k = s0 + t; k < s1; k += 256) {
        unsigned u = binned[k];
        int p = atomicAdd(&cur[u >> 24], 1);
        eidx[s0 + p] = (int)(u & 0xFFFFFF);
    }
}

// ---------------- fused layer-1 gather + dense + z projection ------------------
// one thread per node: register gather of agg4, then k-loop with wave-uniform
// weight reads (compiler emits scalar loads), z = (relu(dinv*agg4@W1+b1)@C)*dinv
__global__ void k_gxz(const float4* __restrict__ xs, const int* __restrict__ eidx,
                      const int* __restrict__ off, const int* __restrict__ cnt,
                      const float* __restrict__ dinv, const float* __restrict__ W1,
                      const float* __restrict__ b1, const float* __restrict__ C,
                      uint4* __restrict__ z, int n) {
    int i = blockIdx.x * 256 + threadIdx.x;
    if (i >= n) return;
    float4 a = xs[i];                       // self-loop
    int o = off[i], c = cnt[i];
    int k = 0;
    for (; k + 8 <= c; k += 8) {
        int id[8];
#pragma unroll
        for (int j = 0; j < 8; j++) id[j] = eidx[o + k + j];
        float4 vv[8];
#pragma unroll
        for (int j = 0; j < 8; j++) vv[j] = xs[id[j]];
#pragma unroll
        for (int j = 0; j < 8; j++) {
            a.x += vv[j].x; a.y += vv[j].y; a.z += vv[j].z; a.w += vv[j].w;
        }
    }
    for (; k < c; k++) {
        float4 vv = xs[eidx[o + k]];
        a.x += vv.x; a.y += vv.y; a.z += vv.z; a.w += vv.w;
    }
    float di = dinv[i];
    float z0 = 0.f, z1 = 0.f, z2 = 0.f, z3 = 0.f,
          z4 = 0.f, z5 = 0.f, z6 = 0.f, z7 = 0.f;
#pragma unroll 4
    for (int kk = 0; kk < HID; kk++) {      // all weight indices wave-uniform
        float x1k = fmaxf(di * (a.x * W1[kk] + a.y * W1[HID + kk] +
                                a.z * W1[2 * HID + kk] + a.w * W1[3 * HID + kk])
                          + b1[kk], 0.0f);
        const float* cr = C + kk * NEXP;
        z0 += x1k * cr[0]; z1 += x1k * cr[1];
        z2 += x1k * cr[2]; z3 += x1k * cr[3];
        z4 += x1k * cr[4]; z5 += x1k * cr[5];
        z6 += x1k * cr[6]; z7 += x1k * cr[7];
    }
    uint4 outv;
    outv.x = packbf(z0 * di, z1 * di);
    outv.y = packbf(z2 * di, z3 * di);
    outv.z = packbf(z4 * di, z5 * di);
    outv.w = packbf(z6 * di, z7 * di);
    z[i] = outv;
}

// ---------------- fused gather2 (8-dim bf16 z) + segment pooling ---------------
__global__ void k_gz(const unsigned short* __restrict__ z, const int* __restrict__ eidx,
                     const int* __restrict__ off, const int* __restrict__ cnt,
                     const float* __restrict__ dinv, const int* __restrict__ batch,
                     float* __restrict__ pool, float* __restrict__ pcnt, int n) {
    int t = threadIdx.x;
    int slot = t >> 3;          // 0..31 within block
    int j = t & 7;
    int i0 = blockIdx.x * (32 * NPS) + slot * NPS;
    if (i0 >= n) return;
    int i1 = i0 + NPS < n ? i0 + NPS : n;
    int rep = (blockIdx.x + slot) & (NREP - 1);
    float* rp  = pool + (size_t)rep * NGRAPH * NEXP;
    float* rpc = pcnt + (size_t)rep * NGRAPH;

    int curg = -1;
    float r = 0.0f, runlen = 0.0f;
    for (int i = i0; i < i1; i++) {
        float acc = bf2f(z[(size_t)i * NEXP + j]);   // self-loop
        int o = off[i], c = cnt[i];
        int k = 0;
        for (; k + 4 <= c; k += 4) {
            int s0 = eidx[o + k], s1 = eidx[o + k + 1];
            int s2 = eidx[o + k + 2], s3 = eidx[o + k + 3];
            unsigned short u0 = z[(size_t)s0 * NEXP + j];
            unsigned short u1 = z[(size_t)s1 * NEXP + j];
            unsigned short u2 = z[(size_t)s2 * NEXP + j];
            unsigned short u3 = z[(size_t)s3 * NEXP + j];
            acc += bf2f(u0) + bf2f(u1) + bf2f(u2) + bf2f(u3);
        }
        for (; k < c; k++)
            acc += bf2f(z[(size_t)eidx[o + k] * NEXP + j]);
        float v = dinv[i] * acc;
        int g = batch[i];
        if (g != curg) {                     // slot-uniform branch
            if (curg >= 0) {
                atomicAdd(&rp[curg * NEXP + j], r);
                if (j == 0) atomicAdd(&rpc[curg], runlen);
            }
            curg = g; r = v; runlen = 1.0f;
        } else { r += v; runlen += 1.0f; }
    }
    if (curg >= 0) {
        atomicAdd(&rp[curg * NEXP + j], r);
        if (j == 0) atomicAdd(&rpc[curg], runlen);
    }
}

// ---------------- replica-sum + mean + (blin + b2@Wlin) + log_softmax ----------
__global__ void k_lsm(const float* __restrict__ pool, const float* __restrict__ pcnt,
                      const float* __restrict__ blin, const float* __restrict__ bb2,
                      float* __restrict__ out) {
    int g = threadIdx.x;
    if (g >= NGRAPH) return;
    float p[NEXP];
#pragma unroll
    for (int k = 0; k < NEXP; k++) p[k] = 0.0f;
    float cg = 0.0f;
#pragma unroll
    for (int rr = 0; rr < NREP; rr++) {
#pragma unroll
        for (int k = 0; k < NEXP; k++) p[k] += pool[rr * NGRAPH * NEXP + g * NEXP + k];
        cg += pcnt[rr * NGRAPH + g];
    }
    float inv = 1.0f / fmaxf(cg, 1.0f);
    float v[NEXP], m = -1e30f;
#pragma unroll
    for (int k = 0; k < NEXP; k++) {
        v[k] = p[k] * inv + blin[k] + bb2[k];
        m = fmaxf(m, v[k]);
    }
    float s = 0.0f;
#pragma unroll
    for (int k = 0; k < NEXP; k++) s += expf(v[k] - m);
    float ls = logf(s);
#pragma unroll
    for (int k = 0; k < NEXP; k++) out[g * NEXP + k] = v[k] - m - ls;
}

extern "C" void kernel_launch(void* const* d_in, const int* in_sizes, int n_in,
                              void* d_out, int out_size, void* d_ws, size_t ws_size,
                              hipStream_t stream) {
    const float* an   = (const float*)d_in[0];
    const float* pos  = (const float*)d_in[1];
    const int*   ei   = (const int*)d_in[2];     // [2, E] flat (int32 view)
    const int*   batch= (const int*)d_in[3];
    const float* W1   = (const float*)d_in[4];
    const float* b1   = (const float*)d_in[5];
    const float* W2   = (const float*)d_in[6];
    const float* b2   = (const float*)d_in[7];
    const float* Wlin = (const float*)d_in[8];
    const float* blin = (const float*)d_in[9];
    float* out = (float*)d_out;

    const int n = in_sizes[0];
    const int e = in_sizes[2] / 2;
    const int* src = ei;
    const int* dst = ei + e;

    const int nbuck = (n + 255) >> 8;            // coarse buckets (<= MAXB)
    const int ch    = (e + EPC - 1) / EPC;       // chunks

    // workspace layout (16B-aligned buffers first)
    char* p = (char*)d_ws;
    float4* xs    = (float4*)p;       p += sizeof(float4) * (size_t)n;
    uint4*  z     = (uint4*)p;        p += sizeof(uint4) * (size_t)n;   // bf16[8]/node
    float* C      = (float*)p;        p += sizeof(float) * HID * NEXP;
    float* bb2    = (float*)p;        p += sizeof(float) * NEXP;
    float* dinv   = (float*)p;        p += sizeof(float) * (size_t)n;
    float* pool   = (float*)p;        p += sizeof(float) * NREP * NGRAPH * NEXP;
    float* pcnt   = (float*)p;        p += sizeof(float) * NREP * NGRAPH;
    int*   cnt    = (int*)p;          p += sizeof(int) * (size_t)n;
    int*   off    = (int*)p;          p += sizeof(int) * (size_t)n;
    int*   bcnt8  = (int*)p;          p += sizeof(int) * (MAXB * NXC + 8);
    int*   boff8  = (int*)p;          p += sizeof(int) * (MAXB * NXC + 8);
    int*   gcur8  = (int*)p;          p += sizeof(int) * (MAXB * NXC + 8);
    unsigned* binned = (unsigned*)p;  p += sizeof(unsigned) * (size_t)e;
    int*   eidx   = (int*)p;          p += sizeof(int) * (size_t)e;

    // init + CSR build via dynamic-reservation counting sort (LDS-sorted writes)
    const int initN = NREP * NGRAPH * NEXP + HID * NEXP + NEXP;
    const int initG = initN > MAXB * NXC ? initN : MAXB * NXC;
    k_init0<<<(initG + 255) / 256, 256, 0, stream>>>(pool, pcnt, W2, Wlin, b2, C, bb2, bcnt8);
    k_hist<<<ch, 256, 0, stream>>>(dst, bcnt8, e, nbuck);
    k_cscan<<<1, 512, 0, stream>>>(bcnt8, boff8, gcur8, e, NXC * nbuck);
    k_binA<<<ch, 256, 0, stream>>>(src, dst, gcur8, binned, e, nbuck);
    k_binB<<<nbuck, 256, 0, stream>>>(binned, boff8, an, pos, cnt, off, dinv, xs, eidx, n);

    // fused layer-1 gather + dense + projection to z (8-dim)
    k_gxz<<<(n + 255) / 256, 256, 0, stream>>>(xs, eidx, off, cnt, dinv, W1, b1, C, z, n);

    // layer 2 gather in 8-dim z-space + pooling, then log_softmax
    k_gz<<<(n + 32 * NPS - 1) / (32 * NPS), 256, 0, stream>>>((const unsigned short*)z,
                                                              eidx, off, cnt, dinv,
                                                              batch, pool, pcnt, n);
    k_lsm<<<1, 64, 0, stream>>>(pool, pcnt, blin, bb2, out);
}

// Round 16
// 231.834 us; speedup vs baseline: 4.9378x; 1.3375x over previous
//
#include <hip/hip_runtime.h>
#include <math.h>

#define HID 128
#define NEXP 8
#define NGRAPH 64
#define EPC 2048       // edges per chunk (hist/binA blocks) - measured sweet spot
#define MAXB 512       // max coarse buckets (n <= 131072)
#define NXC 8          // XCD classes (blockIdx&7 heuristic)
#define NREP 8         // pool replicas (atomic-contention spreading)
#define NPS 8          // nodes per 16-lane slot in k_gz

__device__ inline unsigned short f2bf(float f) {
    unsigned u = __float_as_uint(f);
    u += 0x7FFF + ((u >> 16) & 1);          // RNE
    return (unsigned short)(u >> 16);
}
__device__ inline unsigned packbf(float lo, float hi) {
    return (unsigned)f2bf(lo) | ((unsigned)f2bf(hi) << 16);
}
__device__ inline float bf2f(unsigned short u) {
    return __uint_as_float(((unsigned)u) << 16);
}
__device__ inline float bflo(unsigned u) { return __uint_as_float(u << 16); }
__device__ inline float bfhi(unsigned u) { return __uint_as_float(u & 0xFFFF0000u); }

// ---------------- init: pool/pcnt/bcnt8 zero, C = W2@Wlin, bb2 = b2@Wlin -------
__global__ void k_init0(float* __restrict__ pool, float* __restrict__ pcnt,
                        const float* __restrict__ W2, const float* __restrict__ Wlin,
                        const float* __restrict__ b2, float* __restrict__ C,
                        float* __restrict__ bb2, int* __restrict__ bcnt8) {
    int i = blockIdx.x * 256 + threadIdx.x;
    if (i < MAXB * NXC) bcnt8[i] = 0;
    if (i < NREP * NGRAPH * NEXP) pool[i] = 0.0f;
    if (i < NREP * NGRAPH) pcnt[i] = 0.0f;
    int ci = i - NREP * NGRAPH * NEXP;
    if (ci >= 0 && ci < HID * NEXP) {        // C[k][j] = sum_m W2[k][m]*Wlin[m][j]
        int k = ci >> 3, j = ci & 7;
        float s = 0.0f;
        for (int m = 0; m < HID; m++) s += W2[k * HID + m] * Wlin[m * NEXP + j];
        C[ci] = s;
    }
    int bi = ci - HID * NEXP;
    if (bi >= 0 && bi < NEXP) {              // bb2[j] = sum_m b2[m]*Wlin[m][j]
        float s = 0.0f;
        for (int m = 0; m < HID; m++) s += b2[m] * Wlin[m * NEXP + bi];
        bb2[bi] = s;
    }
}

// ---------------- pass 0: per-(bucket, xcd-class) totals -----------------------
__global__ void k_hist(const int* __restrict__ dst, int* __restrict__ bcnt8,
                       int e, int nbuck) {
    __shared__ int h[MAXB];
    int c = blockIdx.x, t = threadIdx.x;
    int x = c & (NXC - 1);
    for (int b = t; b < nbuck; b += 256) h[b] = 0;
    __syncthreads();
    int start = c * EPC;
    int end = start + EPC < e ? start + EPC : e;
    for (int i = start + t; i < end; i += 256)
        atomicAdd(&h[dst[i] >> 8], 1);
    __syncthreads();
    for (int b = t; b < nbuck; b += 256)
        if (h[b]) atomicAdd(&bcnt8[b * NXC + x], h[b]);
}

// ---------------- scan of 8*nbuck entries + cursor init (1 block, 512 thr) -----
__global__ void k_cscan(const int* __restrict__ bcnt8, int* __restrict__ boff8,
                        int* __restrict__ gcur8, int e, int m /* = 8*nbuck */) {
    __shared__ int s[512];
    int t = threadIdx.x;
    int base = t * 8;
    int v[8];
    int sum = 0;
#pragma unroll
    for (int j = 0; j < 8; j++) {
        v[j] = (base + j < m) ? bcnt8[base + j] : 0;
        sum += v[j];
    }
    s[t] = sum;
    __syncthreads();
    for (int d = 1; d < 512; d <<= 1) {
        int x = (t >= d) ? s[t - d] : 0;
        __syncthreads();
        s[t] += x;
        __syncthreads();
    }
    int run = s[t] - sum;               // exclusive
#pragma unroll
    for (int j = 0; j < 8; j++) {
        if (base + j < m) {
            boff8[base + j] = run;
            gcur8[base + j] = run;
        }
        run += v[j];
    }
    if (t == 0) boff8[m] = e;
}

// ---------------- pass A: LDS counting-sort binning, coalesced run writes ------
__global__ void __launch_bounds__(256) k_binA(
        const int* __restrict__ src, const int* __restrict__ dst,
        int* __restrict__ gcur8, unsigned* __restrict__ binned, int e, int nbuck) {
    __shared__ int h[MAXB];
    __shared__ int ssum[256];
    __shared__ int lstart[MAXB];
    __shared__ int lcur[MAXB];
    __shared__ int gbase[MAXB];
    __shared__ unsigned packed[EPC];
    __shared__ unsigned short sbkt[EPC];
    int c = blockIdx.x, t = threadIdx.x;
    int x = c & (NXC - 1);
    int start = c * EPC;
    int m = e - start < EPC ? e - start : EPC;

    int d[8], sv[8];
#pragma unroll
    for (int j = 0; j < 8; j++) {
        int idx = j * 256 + t;
        if (idx < m) { d[j] = dst[start + idx]; sv[j] = src[start + idx]; }
    }
    h[t] = 0; h[t + 256] = 0;
    __syncthreads();
#pragma unroll
    for (int j = 0; j < 8; j++)
        if (j * 256 + t < m) atomicAdd(&h[d[j] >> 8], 1);
    __syncthreads();
    // exclusive scan of 512 counters (2 per thread)
    int v0 = h[2 * t], v1 = h[2 * t + 1];
    int sum = v0 + v1;
    ssum[t] = sum;
    __syncthreads();
    for (int dd = 1; dd < 256; dd <<= 1) {
        int xx = (t >= dd) ? ssum[t - dd] : 0;
        __syncthreads();
        ssum[t] += xx;
        __syncthreads();
    }
    int ex = ssum[t] - sum;
    lstart[2 * t] = ex;     lstart[2 * t + 1] = ex + v0;
    lcur[2 * t]   = ex;     lcur[2 * t + 1]   = ex + v0;
    __syncthreads();
    // global range reservation per touched bucket
    for (int b = t; b < nbuck; b += 256)
        gbase[b] = h[b] ? atomicAdd(&gcur8[b * NXC + x], h[b]) : 0;
    // LDS sort (scatter to dense local ranks)
#pragma unroll
    for (int j = 0; j < 8; j++) {
        if (j * 256 + t < m) {
            int b = d[j] >> 8;
            int p = atomicAdd(&lcur[b], 1);
            packed[p] = ((unsigned)(d[j] & 255) << 24) | (unsigned)sv[j];
            sbkt[p] = (unsigned short)b;
        }
    }
    __syncthreads();
    // coalesced write-out: consecutive local ranks -> consecutive global slots
    for (int idx = t; idx < m; idx += 256) {
        int b = sbkt[idx];
        binned[gbase[b] + (idx - lstart[b])] = packed[idx];
    }
}

// ---------------- pass B: per-bucket fine sort + cnt/off/dinv + xs -------------
__global__ void k_binB(const unsigned* __restrict__ binned, const int* __restrict__ boff8,
                       const float* __restrict__ an, const float* __restrict__ pos,
                       int* __restrict__ cnt, int* __restrict__ off,
                       float* __restrict__ dinv, float4* __restrict__ xs,
                       int* __restrict__ eidx, int n) {
    __shared__ int h[256];
    __shared__ int sc[256];
    __shared__ int cur[256];
    int b = blockIdx.x, t = threadIdx.x;
    int s0 = boff8[b * NXC], s1 = boff8[(b + 1) * NXC];
    h[t] = 0;
    __syncthreads();
    for (int k = s0 + t; k < s1; k += 256)
        atomicAdd(&h[binned[k] >> 24], 1);
    __syncthreads();
    int v = h[t];
    sc[t] = v;
    __syncthreads();
    for (int d = 1; d < 256; d <<= 1) {
        int x = (t >= d) ? sc[t - d] : 0;
        __syncthreads();
        sc[t] += x;
        __syncthreads();
    }
    int ex = sc[t] - v;          // exclusive within bucket
    cur[t] = ex;
    int node = (b << 8) + t;
    if (node < n) {
        float di = rsqrtf((float)v + 1.0f);   // +1 = self-loop
        cnt[node]  = v;
        off[node]  = s0 + ex;
        dinv[node] = di;
        xs[node] = make_float4(an[node] * di, pos[3 * node] * di,
                               pos[3 * node + 1] * di, pos[3 * node + 2] * di);
    }
    __syncthreads();
    for (int k = s0 + t; k < s1; k += 256) {
        unsigned u = binned[k];
        int p = atomicAdd(&cur[u >> 24], 1);
        eidx[s0 + p] = (int)(u & 0xFFFFFF);
    }
}

// ---------------- fused layer-1 gather + dense + z projection ------------------
// one thread per node: register gather of agg4, then k-loop with wave-uniform
// weight reads (compiler emits scalar loads), z = (relu(dinv*agg4@W1+b1)@C)*dinv
__global__ void k_gxz(const float4* __restrict__ xs, const int* __restrict__ eidx,
                      const int* __restrict__ off, const int* __restrict__ cnt,
                      const float* __restrict__ dinv, const float* __restrict__ W1,
                      const float* __restrict__ b1, const float* __restrict__ C,
                      uint4* __restrict__ z, int n) {
    int i = blockIdx.x * 256 + threadIdx.x;
    if (i >= n) return;
    float4 a = xs[i];                       // self-loop
    int o = off[i], c = cnt[i];
    int k = 0;
    for (; k + 8 <= c; k += 8) {
        int id[8];
#pragma unroll
        for (int j = 0; j < 8; j++) id[j] = eidx[o + k + j];
        float4 vv[8];
#pragma unroll
        for (int j = 0; j < 8; j++) vv[j] = xs[id[j]];
#pragma unroll
        for (int j = 0; j < 8; j++) {
            a.x += vv[j].x; a.y += vv[j].y; a.z += vv[j].z; a.w += vv[j].w;
        }
    }
    for (; k < c; k++) {
        float4 vv = xs[eidx[o + k]];
        a.x += vv.x; a.y += vv.y; a.z += vv.z; a.w += vv.w;
    }
    float di = dinv[i];
    float z0 = 0.f, z1 = 0.f, z2 = 0.f, z3 = 0.f,
          z4 = 0.f, z5 = 0.f, z6 = 0.f, z7 = 0.f;
#pragma unroll 4
    for (int kk = 0; kk < HID; kk++) {      // all weight indices wave-uniform
        float x1k = fmaxf(di * (a.x * W1[kk] + a.y * W1[HID + kk] +
                                a.z * W1[2 * HID + kk] + a.w * W1[3 * HID + kk])
                          + b1[kk], 0.0f);
        const float* cr = C + kk * NEXP;
        z0 += x1k * cr[0]; z1 += x1k * cr[1];
        z2 += x1k * cr[2]; z3 += x1k * cr[3];
        z4 += x1k * cr[4]; z5 += x1k * cr[5];
        z6 += x1k * cr[6]; z7 += x1k * cr[7];
    }
    uint4 outv;
    outv.x = packbf(z0 * di, z1 * di);
    outv.y = packbf(z2 * di, z3 * di);
    outv.z = packbf(z4 * di, z5 * di);
    outv.w = packbf(z6 * di, z7 * di);
    z[i] = outv;
}

// ---------------- fused gather2 + pooling: edge-parallel 16-lane slots ---------
// slot = 16 lanes; lane handles every-16th edge, loading the whole 16B z row
// (uint4) and accumulating all 8 components; shfl_xor tree reduces across the
// slot; lanes 0-7 run-accumulate per graph and flush to replicated pool.
__global__ void k_gz(const uint4* __restrict__ z4, const int* __restrict__ eidx,
                     const int* __restrict__ off, const int* __restrict__ cnt,
                     const float* __restrict__ dinv, const int* __restrict__ batch,
                     float* __restrict__ pool, float* __restrict__ pcnt, int n) {
    int t = threadIdx.x;
    int slot = t >> 4;          // 0..15 within block
    int l = t & 15;             // lane within slot
    int i0 = blockIdx.x * (16 * NPS) + slot * NPS;
    if (i0 >= n) return;
    int i1 = i0 + NPS < n ? i0 + NPS : n;
    int rep = (blockIdx.x + slot) & (NREP - 1);
    float* rp  = pool + (size_t)rep * NGRAPH * NEXP;
    float* rpc = pcnt + (size_t)rep * NGRAPH;

    int curg = -1;
    float r = 0.0f, runlen = 0.0f;
    int j = l & 7;
    for (int i = i0; i < i1; i++) {
        float a0 = 0.f, a1 = 0.f, a2 = 0.f, a3 = 0.f,
              a4 = 0.f, a5 = 0.f, a6 = 0.f, a7 = 0.f;
        int o = off[i], c = cnt[i];
        for (int k = l; k < c; k += 16) {
            uint4 zr = z4[eidx[o + k]];
            a0 += bflo(zr.x); a1 += bfhi(zr.x);
            a2 += bflo(zr.y); a3 += bfhi(zr.y);
            a4 += bflo(zr.z); a5 += bfhi(zr.z);
            a6 += bflo(zr.w); a7 += bfhi(zr.w);
        }
        if (l == 0) {                        // self-loop once
            uint4 zr = z4[i];
            a0 += bflo(zr.x); a1 += bfhi(zr.x);
            a2 += bflo(zr.y); a3 += bfhi(zr.y);
            a4 += bflo(zr.z); a5 += bfhi(zr.z);
            a6 += bflo(zr.w); a7 += bfhi(zr.w);
        }
#pragma unroll
        for (int m = 1; m < 16; m <<= 1) {
            a0 += __shfl_xor(a0, m, 64); a1 += __shfl_xor(a1, m, 64);
            a2 += __shfl_xor(a2, m, 64); a3 += __shfl_xor(a3, m, 64);
            a4 += __shfl_xor(a4, m, 64); a5 += __shfl_xor(a5, m, 64);
            a6 += __shfl_xor(a6, m, 64); a7 += __shfl_xor(a7, m, 64);
        }
        // pick this lane's component (lanes 8-15 mirror 0-7; only 0-7 flush)
        float aj;
        switch (j) {
            case 0: aj = a0; break; case 1: aj = a1; break;
            case 2: aj = a2; break; case 3: aj = a3; break;
            case 4: aj = a4; break; case 5: aj = a5; break;
            case 6: aj = a6; break; default: aj = a7; break;
        }
        float v = dinv[i] * aj;
        int g = batch[i];
        if (g != curg) {                     // slot-uniform branch
            if (curg >= 0 && l < 8) {
                atomicAdd(&rp[curg * NEXP + j], r);
                if (l == 0) atomicAdd(&rpc[curg], runlen);
            }
            curg = g; r = v; runlen = 1.0f;
        } else { r += v; runlen += 1.0f; }
    }
    if (curg >= 0 && l < 8) {
        atomicAdd(&rp[curg * NEXP + j], r);
        if (l == 0) atomicAdd(&rpc[curg], runlen);
    }
}

// ---------------- replica-sum + mean + (blin + b2@Wlin) + log_softmax ----------
__global__ void k_lsm(const float* __restrict__ pool, const float* __restrict__ pcnt,
                      const float* __restrict__ blin, const float* __restrict__ bb2,
                      float* __restrict__ out) {
    int g = threadIdx.x;
    if (g >= NGRAPH) return;
    float p[NEXP];
#pragma unroll
    for (int k = 0; k < NEXP; k++) p[k] = 0.0f;
    float cg = 0.0f;
#pragma unroll
    for (int rr = 0; rr < NREP; rr++) {
#pragma unroll
        for (int k = 0; k < NEXP; k++) p[k] += pool[rr * NGRAPH * NEXP + g * NEXP + k];
        cg += pcnt[rr * NGRAPH + g];
    }
    float inv = 1.0f / fmaxf(cg, 1.0f);
    float v[NEXP], m = -1e30f;
#pragma unroll
    for (int k = 0; k < NEXP; k++) {
        v[k] = p[k] * inv + blin[k] + bb2[k];
        m = fmaxf(m, v[k]);
    }
    float s = 0.0f;
#pragma unroll
    for (int k = 0; k < NEXP; k++) s += expf(v[k] - m);
    float ls = logf(s);
#pragma unroll
    for (int k = 0; k < NEXP; k++) out[g * NEXP + k] = v[k] - m - ls;
}

extern "C" void kernel_launch(void* const* d_in, const int* in_sizes, int n_in,
                              void* d_out, int out_size, void* d_ws, size_t ws_size,
                              hipStream_t stream) {
    const float* an   = (const float*)d_in[0];
    const float* pos  = (const float*)d_in[1];
    const int*   ei   = (const int*)d_in[2];     // [2, E] flat (int32 view)
    const int*   batch= (const int*)d_in[3];
    const float* W1   = (const float*)d_in[4];
    const float* b1   = (const float*)d_in[5];
    const float* W2   = (const float*)d_in[6];
    const float* b2   = (const float*)d_in[7];
    const float* Wlin = (const float*)d_in[8];
    const float* blin = (const float*)d_in[9];
    float* out = (float*)d_out;

    const int n = in_sizes[0];
    const int e = in_sizes[2] / 2;
    const int* src = ei;
    const int* dst = ei + e;

    const int nbuck = (n + 255) >> 8;            // coarse buckets (<= MAXB)
    const int ch    = (e + EPC - 1) / EPC;       // chunks

    // workspace layout (16B-aligned buffers first)
    char* p = (char*)d_ws;
    float4* xs    = (float4*)p;       p += sizeof(float4) * (size_t)n;
    uint4*  z     = (uint4*)p;        p += sizeof(uint4) * (size_t)n;   // bf16[8]/node
    float* C      = (float*)p;        p += sizeof(float) * HID * NEXP;
    float* bb2    = (float*)p;        p += sizeof(float) * NEXP;
    float* dinv   = (float*)p;        p += sizeof(float) * (size_t)n;
    float* pool   = (float*)p;        p += sizeof(float) * NREP * NGRAPH * NEXP;
    float* pcnt   = (float*)p;        p += sizeof(float) * NREP * NGRAPH;
    int*   cnt    = (int*)p;          p += sizeof(int) * (size_t)n;
    int*   off    = (int*)p;          p += sizeof(int) * (size_t)n;
    int*   bcnt8  = (int*)p;          p += sizeof(int) * (MAXB * NXC + 8);
    int*   boff8  = (int*)p;          p += sizeof(int) * (MAXB * NXC + 8);
    int*   gcur8  = (int*)p;          p += sizeof(int) * (MAXB * NXC + 8);
    unsigned* binned = (unsigned*)p;  p += sizeof(unsigned) * (size_t)e;
    int*   eidx   = (int*)p;          p += sizeof(int) * (size_t)e;

    // init + CSR build via dynamic-reservation counting sort (LDS-sorted writes)
    const int initN = NREP * NGRAPH * NEXP + HID * NEXP + NEXP;
    const int initG = initN > MAXB * NXC ? initN : MAXB * NXC;
    k_init0<<<(initG + 255) / 256, 256, 0, stream>>>(pool, pcnt, W2, Wlin, b2, C, bb2, bcnt8);
    k_hist<<<ch, 256, 0, stream>>>(dst, bcnt8, e, nbuck);
    k_cscan<<<1, 512, 0, stream>>>(bcnt8, boff8, gcur8, e, NXC * nbuck);
    k_binA<<<ch, 256, 0, stream>>>(src, dst, gcur8, binned, e, nbuck);
    k_binB<<<nbuck, 256, 0, stream>>>(binned, boff8, an, pos, cnt, off, dinv, xs, eidx, n);

    // fused layer-1 gather + dense + projection to z (8-dim)
    k_gxz<<<(n + 255) / 256, 256, 0, stream>>>(xs, eidx, off, cnt, dinv, W1, b1, C, z, n);

    // layer 2 gather in 8-dim z-space + pooling, then log_softmax
    k_gz<<<(n + 16 * NPS - 1) / (16 * NPS), 256, 0, stream>>>(z, eidx, off, cnt, dinv,
                                                              batch, pool, pcnt, n);
    k_lsm<<<1, 64, 0, stream>>>(pool, pcnt, blin, bb2, out);
}

// Round 17
// 199.049 us; speedup vs baseline: 5.7511x; 1.1647x over previous
//
#include <hip/hip_runtime.h>
#include <math.h>

#define HID 128
#define NEXP 8
#define NGRAPH 64
#define EPC 2048       // edges per chunk (binA blocks) - measured sweet spot
#define MAXB 512       // max coarse buckets (n <= 131072)
#define NXC 8          // XCD classes (blockIdx&7 heuristic)
#define NREP 8         // pool replicas (atomic-contention spreading)
#define NPS 8          // nodes per 16-lane slot in k_gz

__device__ inline unsigned short f2bf(float f) {
    unsigned u = __float_as_uint(f);
    u += 0x7FFF + ((u >> 16) & 1);          // RNE
    return (unsigned short)(u >> 16);
}
__device__ inline unsigned packbf(float lo, float hi) {
    return (unsigned)f2bf(lo) | ((unsigned)f2bf(hi) << 16);
}
__device__ inline float bflo(unsigned u) { return __uint_as_float(u << 16); }
__device__ inline float bfhi(unsigned u) { return __uint_as_float(u & 0xFFFF0000u); }

// ---------------- init: pool/pcnt zero, gcur8 = region bases, C, bb2 -----------
__global__ void k_init0(float* __restrict__ pool, float* __restrict__ pcnt,
                        const float* __restrict__ W2, const float* __restrict__ Wlin,
                        const float* __restrict__ b2, float* __restrict__ C,
                        float* __restrict__ bb2, int* __restrict__ gcur8,
                        int mregions, int capx) {
    int i = blockIdx.x * 256 + threadIdx.x;
    if (i < mregions) gcur8[i] = i * capx;
    if (i < NREP * NGRAPH * NEXP) pool[i] = 0.0f;
    if (i < NREP * NGRAPH) pcnt[i] = 0.0f;
    int ci = i - NREP * NGRAPH * NEXP;
    if (ci >= 0 && ci < HID * NEXP) {        // C[k][j] = sum_m W2[k][m]*Wlin[m][j]
        int k = ci >> 3, j = ci & 7;
        float s = 0.0f;
        for (int m = 0; m < HID; m++) s += W2[k * HID + m] * Wlin[m * NEXP + j];
        C[ci] = s;
    }
    int bi = ci - HID * NEXP;
    if (bi >= 0 && bi < NEXP) {              // bb2[j] = sum_m b2[m]*Wlin[m][j]
        float s = 0.0f;
        for (int m = 0; m < HID; m++) s += b2[m] * Wlin[m * NEXP + bi];
        bb2[bi] = s;
    }
}

// ---------------- pass A: LDS counting-sort binning into fixed regions ---------
// no pre-scan: each chunk reserves from gcur8[b*NXC+x] (region base pre-set);
// shfl-based scan (1 barrier) replaces the 16-barrier ladder.
__global__ void __launch_bounds__(256) k_binA(
        const int* __restrict__ src, const int* __restrict__ dst,
        int* __restrict__ gcur8, unsigned* __restrict__ binned, int e, int nbuck) {
    __shared__ int h[MAXB];
    __shared__ int lstart[MAXB];
    __shared__ int lcur[MAXB];
    __shared__ int gbase[MAXB];
    __shared__ int wtot[4];
    __shared__ unsigned packed[EPC];
    __shared__ unsigned short sbkt[EPC];
    int c = blockIdx.x, t = threadIdx.x;
    int w = t >> 6, lane = t & 63;
    int x = c & (NXC - 1);
    int start = c * EPC;
    int m = e - start < EPC ? e - start : EPC;

    int d[8], sv[8];
#pragma unroll
    for (int j = 0; j < 8; j++) {
        int idx = j * 256 + t;
        if (idx < m) { d[j] = dst[start + idx]; sv[j] = src[start + idx]; }
    }
    h[t] = 0; h[t + 256] = 0;
    __syncthreads();
#pragma unroll
    for (int j = 0; j < 8; j++)
        if (j * 256 + t < m) atomicAdd(&h[d[j] >> 8], 1);
    __syncthreads();
    // shfl-based exclusive scan of 512 counters (2 per thread)
    int v0 = h[2 * t], v1 = h[2 * t + 1];
    int sum = v0 + v1;
    int incl = sum;
#pragma unroll
    for (int dd = 1; dd < 64; dd <<= 1) {
        int y = __shfl_up(incl, dd, 64);
        if (lane >= dd) incl += y;
    }
    if (lane == 63) wtot[w] = incl;
    __syncthreads();
    int pre = 0;
#pragma unroll
    for (int ww = 0; ww < 4; ww++) pre += (ww < w) ? wtot[ww] : 0;
    int ex = pre + incl - sum;
    lstart[2 * t] = ex;     lstart[2 * t + 1] = ex + v0;
    lcur[2 * t]   = ex;     lcur[2 * t + 1]   = ex + v0;
    // global range reservation per touched bucket (fixed-capacity regions)
    for (int b = t; b < nbuck; b += 256)
        gbase[b] = h[b] ? atomicAdd(&gcur8[b * NXC + x], h[b]) : 0;
    __syncthreads();
    // LDS sort (scatter to dense local ranks)
#pragma unroll
    for (int j = 0; j < 8; j++) {
        if (j * 256 + t < m) {
            int b = d[j] >> 8;
            int p = atomicAdd(&lcur[b], 1);
            packed[p] = ((unsigned)(d[j] & 255) << 24) | (unsigned)sv[j];
            sbkt[p] = (unsigned short)b;
        }
    }
    __syncthreads();
    // coalesced write-out: consecutive local ranks -> consecutive global slots
    for (int idx = t; idx < m; idx += 256) {
        int b = sbkt[idx];
        binned[gbase[b] + (idx - lstart[b])] = packed[idx];
    }
}

// ---------------- pass B: per-bucket fine sort + cnt/off/dinv + xs -------------
// bucket b's edges live in 8 sub-ranges [(b*8+x)*capx, gcur8[b*8+x]).
__global__ void k_binB(const unsigned* __restrict__ binned, const int* __restrict__ gcur8,
                       const float* __restrict__ an, const float* __restrict__ pos,
                       int* __restrict__ cnt, int* __restrict__ off,
                       float* __restrict__ dinv, float4* __restrict__ xs,
                       int* __restrict__ eidx, int n, int capx) {
    __shared__ int h[256];
    __shared__ int cur[256];
    __shared__ int wtot[4];
    int b = blockIdx.x, t = threadIdx.x;
    int w = t >> 6, lane = t & 63;
    int cbase = b * NXC;
    int ob = cbase * capx;              // bucket's eidx output base
    h[t] = 0;
    __syncthreads();
#pragma unroll
    for (int x = 0; x < NXC; x++) {
        int rs = (cbase + x) * capx, re = gcur8[cbase + x];
        for (int k = rs + t; k < re; k += 256)
            atomicAdd(&h[binned[k] >> 24], 1);
    }
    __syncthreads();
    // shfl-based exclusive scan of 256 counters
    int v = h[t];
    int incl = v;
#pragma unroll
    for (int dd = 1; dd < 64; dd <<= 1) {
        int y = __shfl_up(incl, dd, 64);
        if (lane >= dd) incl += y;
    }
    if (lane == 63) wtot[w] = incl;
    __syncthreads();
    int pre = 0;
#pragma unroll
    for (int ww = 0; ww < 4; ww++) pre += (ww < w) ? wtot[ww] : 0;
    int ex = pre + incl - v;            // exclusive within bucket
    cur[t] = ex;
    int node = (b << 8) + t;
    if (node < n) {
        float di = rsqrtf((float)v + 1.0f);   // +1 = self-loop
        cnt[node]  = v;
        off[node]  = ob + ex;
        dinv[node] = di;
        xs[node] = make_float4(an[node] * di, pos[3 * node] * di,
                               pos[3 * node + 1] * di, pos[3 * node + 2] * di);
    }
    __syncthreads();
#pragma unroll
    for (int x = 0; x < NXC; x++) {
        int rs = (cbase + x) * capx, re = gcur8[cbase + x];
        for (int k = rs + t; k < re; k += 256) {
            unsigned u = binned[k];
            int p = atomicAdd(&cur[u >> 24], 1);
            eidx[ob + p] = (int)(u & 0xFFFFFF);
        }
    }
}

// ---------------- fused layer-1 gather + dense + z projection ------------------
__global__ void k_gxz(const float4* __restrict__ xs, const int* __restrict__ eidx,
                      const int* __restrict__ off, const int* __restrict__ cnt,
                      const float* __restrict__ dinv, const float* __restrict__ W1,
                      const float* __restrict__ b1, const float* __restrict__ C,
                      uint4* __restrict__ z, int n) {
    int i = blockIdx.x * 256 + threadIdx.x;
    if (i >= n) return;
    float4 a = xs[i];                       // self-loop
    int o = off[i], c = cnt[i];
    int k = 0;
    for (; k + 8 <= c; k += 8) {
        int id[8];
#pragma unroll
        for (int j = 0; j < 8; j++) id[j] = eidx[o + k + j];
        float4 vv[8];
#pragma unroll
        for (int j = 0; j < 8; j++) vv[j] = xs[id[j]];
#pragma unroll
        for (int j = 0; j < 8; j++) {
            a.x += vv[j].x; a.y += vv[j].y; a.z += vv[j].z; a.w += vv[j].w;
        }
    }
    for (; k < c; k++) {
        float4 vv = xs[eidx[o + k]];
        a.x += vv.x; a.y += vv.y; a.z += vv.z; a.w += vv.w;
    }
    float di = dinv[i];
    float z0 = 0.f, z1 = 0.f, z2 = 0.f, z3 = 0.f,
          z4 = 0.f, z5 = 0.f, z6 = 0.f, z7 = 0.f;
#pragma unroll 4
    for (int kk = 0; kk < HID; kk++) {      // all weight indices wave-uniform
        float x1k = fmaxf(di * (a.x * W1[kk] + a.y * W1[HID + kk] +
                                a.z * W1[2 * HID + kk] + a.w * W1[3 * HID + kk])
                          + b1[kk], 0.0f);
        const float* cr = C + kk * NEXP;
        z0 += x1k * cr[0]; z1 += x1k * cr[1];
        z2 += x1k * cr[2]; z3 += x1k * cr[3];
        z4 += x1k * cr[4]; z5 += x1k * cr[5];
        z6 += x1k * cr[6]; z7 += x1k * cr[7];
    }
    uint4 outv;
    outv.x = packbf(z0 * di, z1 * di);
    outv.y = packbf(z2 * di, z3 * di);
    outv.z = packbf(z4 * di, z5 * di);
    outv.w = packbf(z6 * di, z7 * di);
    z[i] = outv;
}

// ---------------- fused gather2 + pooling: edge-parallel 16-lane slots ---------
__global__ void k_gz(const uint4* __restrict__ z4, const int* __restrict__ eidx,
                     const int* __restrict__ off, const int* __restrict__ cnt,
                     const float* __restrict__ dinv, const int* __restrict__ batch,
                     float* __restrict__ pool, float* __restrict__ pcnt, int n) {
    int t = threadIdx.x;
    int slot = t >> 4;          // 0..15 within block
    int l = t & 15;             // lane within slot
    int i0 = blockIdx.x * (16 * NPS) + slot * NPS;
    if (i0 >= n) return;
    int i1 = i0 + NPS < n ? i0 + NPS : n;
    int rep = (blockIdx.x + slot) & (NREP - 1);
    float* rp  = pool + (size_t)rep * NGRAPH * NEXP;
    float* rpc = pcnt + (size_t)rep * NGRAPH;

    int curg = -1;
    float r = 0.0f, runlen = 0.0f;
    int j = l & 7;
    for (int i = i0; i < i1; i++) {
        float a0 = 0.f, a1 = 0.f, a2 = 0.f, a3 = 0.f,
              a4 = 0.f, a5 = 0.f, a6 = 0.f, a7 = 0.f;
        int o = off[i], c = cnt[i];
        for (int k = l; k < c; k += 16) {
            uint4 zr = z4[eidx[o + k]];
            a0 += bflo(zr.x); a1 += bfhi(zr.x);
            a2 += bflo(zr.y); a3 += bfhi(zr.y);
            a4 += bflo(zr.z); a5 += bfhi(zr.z);
            a6 += bflo(zr.w); a7 += bfhi(zr.w);
        }
        if (l == 0) {                        // self-loop once
            uint4 zr = z4[i];
            a0 += bflo(zr.x); a1 += bfhi(zr.x);
            a2 += bflo(zr.y); a3 += bfhi(zr.y);
            a4 += bflo(zr.z); a5 += bfhi(zr.z);
            a6 += bflo(zr.w); a7 += bfhi(zr.w);
        }
#pragma unroll
        for (int m = 1; m < 16; m <<= 1) {
            a0 += __shfl_xor(a0, m, 64); a1 += __shfl_xor(a1, m, 64);
            a2 += __shfl_xor(a2, m, 64); a3 += __shfl_xor(a3, m, 64);
            a4 += __shfl_xor(a4, m, 64); a5 += __shfl_xor(a5, m, 64);
            a6 += __shfl_xor(a6, m, 64); a7 += __shfl_xor(a7, m, 64);
        }
        float aj;
        switch (j) {
            case 0: aj = a0; break; case 1: aj = a1; break;
            case 2: aj = a2; break; case 3: aj = a3; break;
            case 4: aj = a4; break; case 5: aj = a5; break;
            case 6: aj = a6; break; default: aj = a7; break;
        }
        float v = dinv[i] * aj;
        int g = batch[i];
        if (g != curg) {                     // slot-uniform branch
            if (curg >= 0 && l < 8) {
                atomicAdd(&rp[curg * NEXP + j], r);
                if (l == 0) atomicAdd(&rpc[curg], runlen);
            }
            curg = g; r = v; runlen = 1.0f;
        } else { r += v; runlen += 1.0f; }
    }
    if (curg >= 0 && l < 8) {
        atomicAdd(&rp[curg * NEXP + j], r);
        if (l == 0) atomicAdd(&rpc[curg], runlen);
    }
}

// ---------------- replica-sum + mean + (blin + b2@Wlin) + log_softmax ----------
__global__ void k_lsm(const float* __restrict__ pool, const float* __restrict__ pcnt,
                      const float* __restrict__ blin, const float* __restrict__ bb2,
                      float* __restrict__ out) {
    int g = threadIdx.x;
    if (g >= NGRAPH) return;
    float p[NEXP];
#pragma unroll
    for (int k = 0; k < NEXP; k++) p[k] = 0.0f;
    float cg = 0.0f;
#pragma unroll
    for (int rr = 0; rr < NREP; rr++) {
#pragma unroll
        for (int k = 0; k < NEXP; k++) p[k] += pool[rr * NGRAPH * NEXP + g * NEXP + k];
        cg += pcnt[rr * NGRAPH + g];
    }
    float inv = 1.0f / fmaxf(cg, 1.0f);
    float v[NEXP], m = -1e30f;
#pragma unroll
    for (int k = 0; k < NEXP; k++) {
        v[k] = p[k] * inv + blin[k] + bb2[k];
        m = fmaxf(m, v[k]);
    }
    float s = 0.0f;
#pragma unroll
    for (int k = 0; k < NEXP; k++) s += expf(v[k] - m);
    float ls = logf(s);
#pragma unroll
    for (int k = 0; k < NEXP; k++) out[g * NEXP + k] = v[k] - m - ls;
}

extern "C" void kernel_launch(void* const* d_in, const int* in_sizes, int n_in,
                              void* d_out, int out_size, void* d_ws, size_t ws_size,
                              hipStream_t stream) {
    const float* an   = (const float*)d_in[0];
    const float* pos  = (const float*)d_in[1];
    const int*   ei   = (const int*)d_in[2];     // [2, E] flat (int32 view)
    const int*   batch= (const int*)d_in[3];
    const float* W1   = (const float*)d_in[4];
    const float* b1   = (const float*)d_in[5];
    const float* W2   = (const float*)d_in[6];
    const float* b2   = (const float*)d_in[7];
    const float* Wlin = (const float*)d_in[8];
    const float* blin = (const float*)d_in[9];
    float* out = (float*)d_out;

    const int n = in_sizes[0];
    const int e = in_sizes[2] / 2;
    const int* src = ei;
    const int* dst = ei + e;

    const int nbuck = (n + 255) >> 8;            // coarse buckets (<= MAXB)
    const int ch    = (e + EPC - 1) / EPC;       // chunks
    const int mreg  = nbuck * NXC;               // fixed-capacity regions
    const int capx  = 2 * (e / (mreg > 0 ? mreg : 1)) + 256;   // ~34 sigma slack

    // workspace layout (16B-aligned buffers first)
    char* p = (char*)d_ws;
    float4* xs    = (float4*)p;       p += sizeof(float4) * (size_t)n;
    uint4*  z     = (uint4*)p;        p += sizeof(uint4) * (size_t)n;   // bf16[8]/node
    float* C      = (float*)p;        p += sizeof(float) * HID * NEXP;
    float* bb2    = (float*)p;        p += sizeof(float) * NEXP;
    float* dinv   = (float*)p;        p += sizeof(float) * (size_t)n;
    float* pool   = (float*)p;        p += sizeof(float) * NREP * NGRAPH * NEXP;
    float* pcnt   = (float*)p;        p += sizeof(float) * NREP * NGRAPH;
    int*   cnt    = (int*)p;          p += sizeof(int) * (size_t)n;
    int*   off    = (int*)p;          p += sizeof(int) * (size_t)n;
    int*   gcur8  = (int*)p;          p += sizeof(int) * (mreg + 8);
    unsigned* binned = (unsigned*)p;  p += sizeof(unsigned) * (size_t)mreg * capx;
    int*   eidx   = (int*)p;          p += sizeof(int) * (size_t)mreg * capx;

    // init (region bases replace hist+cscan) + binning + fine sort
    const int initN = NREP * NGRAPH * NEXP + HID * NEXP + NEXP;
    const int initG = initN > mreg ? initN : mreg;
    k_init0<<<(initG + 255) / 256, 256, 0, stream>>>(pool, pcnt, W2, Wlin, b2, C,
                                                     bb2, gcur8, mreg, capx);
    k_binA<<<ch, 256, 0, stream>>>(src, dst, gcur8, binned, e, nbuck);
    k_binB<<<nbuck, 256, 0, stream>>>(binned, gcur8, an, pos, cnt, off, dinv,
                                      xs, eidx, n, capx);

    // fused layer-1 gather + dense + projection to z (8-dim)
    k_gxz<<<(n + 255) / 256, 256, 0, stream>>>(xs, eidx, off, cnt, dinv, W1, b1, C, z, n);

    // layer 2 gather in 8-dim z-space + pooling, then log_softmax
    k_gz<<<(n + 16 * NPS - 1) / (16 * NPS), 256, 0, stream>>>(z, eidx, off, cnt, dinv,
                                                              batch, pool, pcnt, n);
    k_lsm<<<1, 64, 0, stream>>>(pool, pcnt, blin, bb2, out);
}

// Round 18
// 196.888 us; speedup vs baseline: 5.8142x; 1.0110x over previous
//
#include <hip/hip_runtime.h>
#include <math.h>

#define HID 128
#define NEXP 8
#define NGRAPH 64
#define EPC 2048       // edges per chunk (binA blocks) - measured sweet spot
#define MAXB 512       // max coarse buckets (n <= 131072)
#define NXC 8          // XCD classes (blockIdx&7 heuristic)
#define NREP 8         // pool replicas (atomic-contention spreading)
#define NPS 8          // nodes per 16-lane slot in k_gz

__device__ inline unsigned short f2bf(float f) {
    unsigned u = __float_as_uint(f);
    u += 0x7FFF + ((u >> 16) & 1);          // RNE
    return (unsigned short)(u >> 16);
}
__device__ inline unsigned packbf(float lo, float hi) {
    return (unsigned)f2bf(lo) | ((unsigned)f2bf(hi) << 16);
}
__device__ inline float bflo(unsigned u) { return __uint_as_float(u << 16); }
__device__ inline float bfhi(unsigned u) { return __uint_as_float(u & 0xFFFF0000u); }

// ---------------- init: pool/pcnt zero, gcur8 = region bases, C, bb2 -----------
__global__ void k_init0(float* __restrict__ pool, float* __restrict__ pcnt,
                        const float* __restrict__ W2, const float* __restrict__ Wlin,
                        const float* __restrict__ b2, float* __restrict__ C,
                        float* __restrict__ bb2, int* __restrict__ gcur8,
                        int mregions, int capx) {
    int i = blockIdx.x * 256 + threadIdx.x;
    if (i < mregions) gcur8[i] = i * capx;
    if (i < NREP * NGRAPH * NEXP) pool[i] = 0.0f;
    if (i < NREP * NGRAPH) pcnt[i] = 0.0f;
    int ci = i - NREP * NGRAPH * NEXP;
    if (ci >= 0 && ci < HID * NEXP) {        // C[k][j] = sum_m W2[k][m]*Wlin[m][j]
        int k = ci >> 3, j = ci & 7;
        float s = 0.0f;
        for (int m = 0; m < HID; m++) s += W2[k * HID + m] * Wlin[m * NEXP + j];
        C[ci] = s;
    }
    int bi = ci - HID * NEXP;
    if (bi >= 0 && bi < NEXP) {              // bb2[j] = sum_m b2[m]*Wlin[m][j]
        float s = 0.0f;
        for (int m = 0; m < HID; m++) s += b2[m] * Wlin[m * NEXP + bi];
        bb2[bi] = s;
    }
}

// ---------------- pass A: LDS counting-sort binning into fixed regions ---------
// int4 edge loads (8 consecutive edges/thread); dual LDS histograms halve
// same-address atomic contention; shfl-based scan (1 barrier).
__global__ void __launch_bounds__(256) k_binA(
        const int* __restrict__ src, const int* __restrict__ dst,
        int* __restrict__ gcur8, unsigned* __restrict__ binned, int e, int nbuck) {
    __shared__ int h0[MAXB];
    __shared__ int h1[MAXB];
    __shared__ int lstart[MAXB];
    __shared__ int lcur[MAXB];
    __shared__ int gbase[MAXB];
    __shared__ int wtot[4];
    __shared__ unsigned packed[EPC];
    __shared__ unsigned short sbkt[EPC];
    int c = blockIdx.x, t = threadIdx.x;
    int w = t >> 6, lane = t & 63;
    int x = c & (NXC - 1);
    int start = c * EPC;
    int m = e - start < EPC ? e - start : EPC;

    int d[8], sv[8];
    if (m == EPC) {
        int4 da = ((const int4*)(dst + start))[2 * t];
        int4 db = ((const int4*)(dst + start))[2 * t + 1];
        int4 sa = ((const int4*)(src + start))[2 * t];
        int4 sb = ((const int4*)(src + start))[2 * t + 1];
        d[0] = da.x; d[1] = da.y; d[2] = da.z; d[3] = da.w;
        d[4] = db.x; d[5] = db.y; d[6] = db.z; d[7] = db.w;
        sv[0] = sa.x; sv[1] = sa.y; sv[2] = sa.z; sv[3] = sa.w;
        sv[4] = sb.x; sv[5] = sb.y; sv[6] = sb.z; sv[7] = sb.w;
    } else {
#pragma unroll
        for (int j = 0; j < 8; j++) {
            int idx = t * 8 + j;
            if (idx < m) { d[j] = dst[start + idx]; sv[j] = src[start + idx]; }
        }
    }
    int* hm = (w < 2) ? h0 : h1;
    h0[t] = 0; h0[t + 256] = 0;
    h1[t] = 0; h1[t + 256] = 0;
    __syncthreads();
#pragma unroll
    for (int j = 0; j < 8; j++)
        if (t * 8 + j < m) atomicAdd(&hm[d[j] >> 8], 1);
    __syncthreads();
    // shfl-based exclusive scan of 512 counters (2 per thread)
    int v0 = h0[2 * t] + h1[2 * t];
    int v1 = h0[2 * t + 1] + h1[2 * t + 1];
    int sum = v0 + v1;
    int incl = sum;
#pragma unroll
    for (int dd = 1; dd < 64; dd <<= 1) {
        int y = __shfl_up(incl, dd, 64);
        if (lane >= dd) incl += y;
    }
    if (lane == 63) wtot[w] = incl;
    __syncthreads();
    int pre = 0;
#pragma unroll
    for (int ww = 0; ww < 4; ww++) pre += (ww < w) ? wtot[ww] : 0;
    int ex = pre + incl - sum;
    lstart[2 * t] = ex;     lstart[2 * t + 1] = ex + v0;
    lcur[2 * t]   = ex;     lcur[2 * t + 1]   = ex + v0;
    // global range reservation per touched bucket (fixed-capacity regions)
    for (int b = t; b < nbuck; b += 256) {
        int hv = h0[b] + h1[b];
        gbase[b] = hv ? atomicAdd(&gcur8[b * NXC + x], hv) : 0;
    }
    __syncthreads();
    // LDS sort (scatter to dense local ranks)
#pragma unroll
    for (int j = 0; j < 8; j++) {
        if (t * 8 + j < m) {
            int b = d[j] >> 8;
            int p = atomicAdd(&lcur[b], 1);
            packed[p] = ((unsigned)(d[j] & 255) << 24) | (unsigned)sv[j];
            sbkt[p] = (unsigned short)b;
        }
    }
    __syncthreads();
    // coalesced write-out: consecutive local ranks -> consecutive global slots
    for (int idx = t; idx < m; idx += 256) {
        int b = sbkt[idx];
        binned[gbase[b] + (idx - lstart[b])] = packed[idx];
    }
}

// ---------------- pass B: per-bucket fine sort + cnt/off/dinv + xs -------------
// bucket b's edges live in 8 sub-ranges [(b*8+x)*capx, gcur8[b*8+x]).
__global__ void k_binB(const unsigned* __restrict__ binned, const int* __restrict__ gcur8,
                       const float* __restrict__ an, const float* __restrict__ pos,
                       int* __restrict__ cnt, int* __restrict__ off,
                       float* __restrict__ dinv, float4* __restrict__ xs,
                       int* __restrict__ eidx, int n, int capx) {
    __shared__ int h[256];
    __shared__ int cur[256];
    __shared__ int wtot[4];
    int b = blockIdx.x, t = threadIdx.x;
    int w = t >> 6, lane = t & 63;
    int cbase = b * NXC;
    int ob = cbase * capx;              // bucket's eidx output base
    h[t] = 0;
    __syncthreads();
#pragma unroll
    for (int x = 0; x < NXC; x++) {
        int rs = (cbase + x) * capx, re = gcur8[cbase + x];
        for (int k = rs + t; k < re; k += 256)
            atomicAdd(&h[binned[k] >> 24], 1);
    }
    __syncthreads();
    // shfl-based exclusive scan of 256 counters
    int v = h[t];
    int incl = v;
#pragma unroll
    for (int dd = 1; dd < 64; dd <<= 1) {
        int y = __shfl_up(incl, dd, 64);
        if (lane >= dd) incl += y;
    }
    if (lane == 63) wtot[w] = incl;
    __syncthreads();
    int pre = 0;
#pragma unroll
    for (int ww = 0; ww < 4; ww++) pre += (ww < w) ? wtot[ww] : 0;
    int ex = pre + incl - v;            // exclusive within bucket
    cur[t] = ex;
    int node = (b << 8) + t;
    if (node < n) {
        float di = rsqrtf((float)v + 1.0f);   // +1 = self-loop
        cnt[node]  = v;
        off[node]  = ob + ex;
        dinv[node] = di;
        xs[node] = make_float4(an[node] * di, pos[3 * node] * di,
                               pos[3 * node + 1] * di, pos[3 * node + 2] * di);
    }
    __syncthreads();
#pragma unroll
    for (int x = 0; x < NXC; x++) {
        int rs = (cbase + x) * capx, re = gcur8[cbase + x];
        for (int k = rs + t; k < re; k += 256) {
            unsigned u = binned[k];
            int p = atomicAdd(&cur[u >> 24], 1);
            eidx[ob + p] = (int)(u & 0xFFFFFF);
        }
    }
}

// ---------------- fused layer-1 gather + dense + z projection ------------------
// 2 threads per node: edge loop split by parity (halved load chain), a combined
// via 4 shfl; dense loop run redundantly (weights stay wave-uniform -> scalar
// loads); even thread stores.
__global__ void k_gxz(const float4* __restrict__ xs, const int* __restrict__ eidx,
                      const int* __restrict__ off, const int* __restrict__ cnt,
                      const float* __restrict__ dinv, const float* __restrict__ W1,
                      const float* __restrict__ b1, const float* __restrict__ C,
                      uint4* __restrict__ z, int n) {
    int tid = blockIdx.x * 256 + threadIdx.x;
    int i = tid >> 1;
    int par = tid & 1;
    if (i >= n) return;
    float4 a = par ? make_float4(0.f, 0.f, 0.f, 0.f) : xs[i];   // self-loop once
    int o = off[i], c = cnt[i];
    int k = par;
    for (; k + 6 < c; k += 8) {
        int i0 = eidx[o + k],     i1 = eidx[o + k + 2];
        int i2 = eidx[o + k + 4], i3 = eidx[o + k + 6];
        float4 v0 = xs[i0], v1 = xs[i1], v2 = xs[i2], v3 = xs[i3];
        a.x += v0.x + v1.x + v2.x + v3.x;
        a.y += v0.y + v1.y + v2.y + v3.y;
        a.z += v0.z + v1.z + v2.z + v3.z;
        a.w += v0.w + v1.w + v2.w + v3.w;
    }
    for (; k < c; k += 2) {
        float4 v0 = xs[eidx[o + k]];
        a.x += v0.x; a.y += v0.y; a.z += v0.z; a.w += v0.w;
    }
    a.x += __shfl_xor(a.x, 1, 64);
    a.y += __shfl_xor(a.y, 1, 64);
    a.z += __shfl_xor(a.z, 1, 64);
    a.w += __shfl_xor(a.w, 1, 64);
    float di = dinv[i];
    float z0 = 0.f, z1 = 0.f, z2 = 0.f, z3 = 0.f,
          z4 = 0.f, z5 = 0.f, z6 = 0.f, z7 = 0.f;
#pragma unroll 4
    for (int kk = 0; kk < HID; kk++) {      // all weight indices wave-uniform
        float x1k = fmaxf(di * (a.x * W1[kk] + a.y * W1[HID + kk] +
                                a.z * W1[2 * HID + kk] + a.w * W1[3 * HID + kk])
                          + b1[kk], 0.0f);
        const float* cr = C + kk * NEXP;
        z0 += x1k * cr[0]; z1 += x1k * cr[1];
        z2 += x1k * cr[2]; z3 += x1k * cr[3];
        z4 += x1k * cr[4]; z5 += x1k * cr[5];
        z6 += x1k * cr[6]; z7 += x1k * cr[7];
    }
    if (par == 0) {
        uint4 outv;
        outv.x = packbf(z0 * di, z1 * di);
        outv.y = packbf(z2 * di, z3 * di);
        outv.z = packbf(z4 * di, z5 * di);
        outv.w = packbf(z6 * di, z7 * di);
        z[i] = outv;
    }
}

// ---------------- fused gather2 + pooling: edge-parallel 16-lane slots ---------
// 20-shfl reduction: xor8+xor4 on 8 accs -> lane holds its q-class partials;
// quad Q=l>>2 selects comp pair (2Q,2Q+1); xor1+xor2 completes; (l&3)==0 flush.
__global__ void k_gz(const uint4* __restrict__ z4, const int* __restrict__ eidx,
                     const int* __restrict__ off, const int* __restrict__ cnt,
                     const float* __restrict__ dinv, const int* __restrict__ batch,
                     float* __restrict__ pool, float* __restrict__ pcnt, int n) {
    int t = threadIdx.x;
    int slot = t >> 4;          // 0..15 within block
    int l = t & 15;             // lane within slot
    int i0 = blockIdx.x * (16 * NPS) + slot * NPS;
    if (i0 >= n) return;
    int i1 = i0 + NPS < n ? i0 + NPS : n;
    int rep = (blockIdx.x + slot) & (NREP - 1);
    float* rp  = pool + (size_t)rep * NGRAPH * NEXP;
    float* rpc = pcnt + (size_t)rep * NGRAPH;
    int Q = l >> 2;

    int curg = -1;
    float r0 = 0.0f, r1 = 0.0f, runlen = 0.0f;
    for (int i = i0; i < i1; i++) {
        float a0 = 0.f, a1 = 0.f, a2 = 0.f, a3 = 0.f,
              a4 = 0.f, a5 = 0.f, a6 = 0.f, a7 = 0.f;
        int o = off[i], c = cnt[i];
        for (int k = l; k < c; k += 16) {
            uint4 zr = z4[eidx[o + k]];
            a0 += bflo(zr.x); a1 += bfhi(zr.x);
            a2 += bflo(zr.y); a3 += bfhi(zr.y);
            a4 += bflo(zr.z); a5 += bfhi(zr.z);
            a6 += bflo(zr.w); a7 += bfhi(zr.w);
        }
        if (l == 0) {                        // self-loop once
            uint4 zr = z4[i];
            a0 += bflo(zr.x); a1 += bfhi(zr.x);
            a2 += bflo(zr.y); a3 += bfhi(zr.y);
            a4 += bflo(zr.z); a5 += bfhi(zr.z);
            a6 += bflo(zr.w); a7 += bfhi(zr.w);
        }
        // rounds 8,4: lane ends with q-class (l&3) partial over all comps
        a0 += __shfl_xor(a0, 8, 64); a1 += __shfl_xor(a1, 8, 64);
        a2 += __shfl_xor(a2, 8, 64); a3 += __shfl_xor(a3, 8, 64);
        a4 += __shfl_xor(a4, 8, 64); a5 += __shfl_xor(a5, 8, 64);
        a6 += __shfl_xor(a6, 8, 64); a7 += __shfl_xor(a7, 8, 64);
        a0 += __shfl_xor(a0, 4, 64); a1 += __shfl_xor(a1, 4, 64);
        a2 += __shfl_xor(a2, 4, 64); a3 += __shfl_xor(a3, 4, 64);
        a4 += __shfl_xor(a4, 4, 64); a5 += __shfl_xor(a5, 4, 64);
        a6 += __shfl_xor(a6, 4, 64); a7 += __shfl_xor(a7, 4, 64);
        // quad Q selects its comp pair (uniform within quad), xor1+xor2 combine
        float r0v, r1v;
        switch (Q) {
            case 0:  r0v = a0; r1v = a1; break;
            case 1:  r0v = a2; r1v = a3; break;
            case 2:  r0v = a4; r1v = a5; break;
            default: r0v = a6; r1v = a7; break;
        }
        r0v += __shfl_xor(r0v, 1, 64); r1v += __shfl_xor(r1v, 1, 64);
        r0v += __shfl_xor(r0v, 2, 64); r1v += __shfl_xor(r1v, 2, 64);
        float di = dinv[i];
        float v0 = di * r0v, v1 = di * r1v;
        int g = batch[i];
        if (g != curg) {                     // slot-uniform branch
            if (curg >= 0 && (l & 3) == 0) {
                atomicAdd(&rp[curg * NEXP + 2 * Q], r0);
                atomicAdd(&rp[curg * NEXP + 2 * Q + 1], r1);
                if (l == 0) atomicAdd(&rpc[curg], runlen);
            }
            curg = g; r0 = v0; r1 = v1; runlen = 1.0f;
        } else { r0 += v0; r1 += v1; runlen += 1.0f; }
    }
    if (curg >= 0 && (l & 3) == 0) {
        atomicAdd(&rp[curg * NEXP + 2 * Q], r0);
        atomicAdd(&rp[curg * NEXP + 2 * Q + 1], r1);
        if (l == 0) atomicAdd(&rpc[curg], runlen);
    }
}

// ---------------- replica-sum + mean + (blin + b2@Wlin) + log_softmax ----------
__global__ void k_lsm(const float* __restrict__ pool, const float* __restrict__ pcnt,
                      const float* __restrict__ blin, const float* __restrict__ bb2,
                      float* __restrict__ out) {
    int g = threadIdx.x;
    if (g >= NGRAPH) return;
    float p[NEXP];
#pragma unroll
    for (int k = 0; k < NEXP; k++) p[k] = 0.0f;
    float cg = 0.0f;
#pragma unroll
    for (int rr = 0; rr < NREP; rr++) {
#pragma unroll
        for (int k = 0; k < NEXP; k++) p[k] += pool[rr * NGRAPH * NEXP + g * NEXP + k];
        cg += pcnt[rr * NGRAPH + g];
    }
    float inv = 1.0f / fmaxf(cg, 1.0f);
    float v[NEXP], m = -1e30f;
#pragma unroll
    for (int k = 0; k < NEXP; k++) {
        v[k] = p[k] * inv + blin[k] + bb2[k];
        m = fmaxf(m, v[k]);
    }
    float s = 0.0f;
#pragma unroll
    for (int k = 0; k < NEXP; k++) s += expf(v[k] - m);
    float ls = logf(s);
#pragma unroll
    for (int k = 0; k < NEXP; k++) out[g * NEXP + k] = v[k] - m - ls;
}

extern "C" void kernel_launch(void* const* d_in, const int* in_sizes, int n_in,
                              void* d_out, int out_size, void* d_ws, size_t ws_size,
                              hipStream_t stream) {
    const float* an   = (const float*)d_in[0];
    const float* pos  = (const float*)d_in[1];
    const int*   ei   = (const int*)d_in[2];     // [2, E] flat (int32 view)
    const int*   batch= (const int*)d_in[3];
    const float* W1   = (const float*)d_in[4];
    const float* b1   = (const float*)d_in[5];
    const float* W2   = (const float*)d_in[6];
    const float* b2   = (const float*)d_in[7];
    const float* Wlin = (const float*)d_in[8];
    const float* blin = (const float*)d_in[9];
    float* out = (float*)d_out;

    const int n = in_sizes[0];
    const int e = in_sizes[2] / 2;
    const int* src = ei;
    const int* dst = ei + e;

    const int nbuck = (n + 255) >> 8;            // coarse buckets (<= MAXB)
    const int ch    = (e + EPC - 1) / EPC;       // chunks
    const int mreg  = nbuck * NXC;               // fixed-capacity regions
    const int capx  = 2 * (e / (mreg > 0 ? mreg : 1)) + 256;   // ~34 sigma slack

    // workspace layout (16B-aligned buffers first)
    char* p = (char*)d_ws;
    float4* xs    = (float4*)p;       p += sizeof(float4) * (size_t)n;
    uint4*  z     = (uint4*)p;        p += sizeof(uint4) * (size_t)n;   // bf16[8]/node
    float* C      = (float*)p;        p += sizeof(float) * HID * NEXP;
    float* bb2    = (float*)p;        p += sizeof(float) * NEXP;
    float* dinv   = (float*)p;        p += sizeof(float) * (size_t)n;
    float* pool   = (float*)p;        p += sizeof(float) * NREP * NGRAPH * NEXP;
    float* pcnt   = (float*)p;        p += sizeof(float) * NREP * NGRAPH;
    int*   cnt    = (int*)p;          p += sizeof(int) * (size_t)n;
    int*   off    = (int*)p;          p += sizeof(int) * (size_t)n;
    int*   gcur8  = (int*)p;          p += sizeof(int) * (mreg + 8);
    unsigned* binned = (unsigned*)p;  p += sizeof(unsigned) * (size_t)mreg * capx;
    int*   eidx   = (int*)p;          p += sizeof(int) * (size_t)mreg * capx;

    // init (region bases replace hist+cscan) + binning + fine sort
    const int initN = NREP * NGRAPH * NEXP + HID * NEXP + NEXP;
    const int initG = initN > mreg ? initN : mreg;
    k_init0<<<(initG + 255) / 256, 256, 0, stream>>>(pool, pcnt, W2, Wlin, b2, C,
                                                     bb2, gcur8, mreg, capx);
    k_binA<<<ch, 256, 0, stream>>>(src, dst, gcur8, binned, e, nbuck);
    k_binB<<<nbuck, 256, 0, stream>>>(binned, gcur8, an, pos, cnt, off, dinv,
                                      xs, eidx, n, capx);

    // fused layer-1 gather + dense + projection to z (2 threads/node)
    k_gxz<<<(2 * n + 255) / 256, 256, 0, stream>>>(xs, eidx, off, cnt, dinv,
                                                   W1, b1, C, z, n);

    // layer 2 gather in 8-dim z-space + pooling, then log_softmax
    k_gz<<<(n + 16 * NPS - 1) / (16 * NPS), 256, 0, stream>>>(z, eidx, off, cnt, dinv,
                                                              batch, pool, pcnt, n);
    k_lsm<<<1, 64, 0, stream>>>(pool, pcnt, blin, bb2, out);
}

// Round 19
// 178.704 us; speedup vs baseline: 6.4058x; 1.1018x over previous
//
#include <hip/hip_runtime.h>
#include <math.h>

#define HID 128
#define NEXP 8
#define NGRAPH 64
#define EPC 4096       // edges per chunk (binA blocks): longer runs -> fewer write txns
#define MAXB 512       // max coarse buckets (n <= 131072)
#define NXC 8          // XCD classes (blockIdx&7 heuristic)
#define NREP 8         // pool replicas (atomic-contention spreading)
#define NPS 8          // nodes per 16-lane slot in k_gz
#define HALF 128       // fine ids per k_binB block

__device__ inline unsigned short f2bf(float f) {
    unsigned u = __float_as_uint(f);
    u += 0x7FFF + ((u >> 16) & 1);          // RNE
    return (unsigned short)(u >> 16);
}
__device__ inline unsigned packbf(float lo, float hi) {
    return (unsigned)f2bf(lo) | ((unsigned)f2bf(hi) << 16);
}
__device__ inline float bflo(unsigned u) { return __uint_as_float(u << 16); }
__device__ inline float bfhi(unsigned u) { return __uint_as_float(u & 0xFFFF0000u); }

// ---------------- init: pool/pcnt zero, gcur8 = region bases, C, bb2 -----------
__global__ void k_init0(float* __restrict__ pool, float* __restrict__ pcnt,
                        const float* __restrict__ W2, const float* __restrict__ Wlin,
                        const float* __restrict__ b2, float* __restrict__ C,
                        float* __restrict__ bb2, int* __restrict__ gcur8,
                        int mregions, int capx) {
    int i = blockIdx.x * 256 + threadIdx.x;
    if (i < mregions) gcur8[i] = i * capx;
    if (i < NREP * NGRAPH * NEXP) pool[i] = 0.0f;
    if (i < NREP * NGRAPH) pcnt[i] = 0.0f;
    int ci = i - NREP * NGRAPH * NEXP;
    if (ci >= 0 && ci < HID * NEXP) {        // C[k][j] = sum_m W2[k][m]*Wlin[m][j]
        int k = ci >> 3, j = ci & 7;
        float s = 0.0f;
        for (int m = 0; m < HID; m++) s += W2[k * HID + m] * Wlin[m * NEXP + j];
        C[ci] = s;
    }
    int bi = ci - HID * NEXP;
    if (bi >= 0 && bi < NEXP) {              // bb2[j] = sum_m b2[m]*Wlin[m][j]
        float s = 0.0f;
        for (int m = 0; m < HID; m++) s += b2[m] * Wlin[m * NEXP + bi];
        bb2[bi] = s;
    }
}

// ---------------- pass A: LDS counting-sort binning into fixed regions ---------
// 16 edges/thread via int4 loads; dual LDS histograms; shfl scan; sorted
// write-out in ~10.5-edge runs (fewer partial-line write transactions).
__global__ void __launch_bounds__(256) k_binA(
        const int* __restrict__ src, const int* __restrict__ dst,
        int* __restrict__ gcur8, unsigned* __restrict__ binned, int e, int nbuck) {
    __shared__ int h0[MAXB];
    __shared__ int h1[MAXB];
    __shared__ int lstart[MAXB];
    __shared__ int lcur[MAXB];
    __shared__ int gbase[MAXB];
    __shared__ int wtot[4];
    __shared__ unsigned packed[EPC];
    __shared__ unsigned short sbkt[EPC];
    int c = blockIdx.x, t = threadIdx.x;
    int w = t >> 6, lane = t & 63;
    int x = c & (NXC - 1);
    int start = c * EPC;
    int m = e - start < EPC ? e - start : EPC;

    int d[16], sv[16];
    if (m == EPC) {
        const int4* d4 = (const int4*)(dst + start);
        const int4* s4 = (const int4*)(src + start);
#pragma unroll
        for (int q = 0; q < 4; q++) {
            int4 dd4 = d4[4 * t + q];
            int4 ss4 = s4[4 * t + q];
            d[4 * q + 0] = dd4.x; d[4 * q + 1] = dd4.y;
            d[4 * q + 2] = dd4.z; d[4 * q + 3] = dd4.w;
            sv[4 * q + 0] = ss4.x; sv[4 * q + 1] = ss4.y;
            sv[4 * q + 2] = ss4.z; sv[4 * q + 3] = ss4.w;
        }
    } else {
#pragma unroll
        for (int j = 0; j < 16; j++) {
            int idx = t * 16 + j;
            if (idx < m) { d[j] = dst[start + idx]; sv[j] = src[start + idx]; }
        }
    }
    int* hm = (w < 2) ? h0 : h1;
    h0[t] = 0; h0[t + 256] = 0;
    h1[t] = 0; h1[t + 256] = 0;
    __syncthreads();
#pragma unroll
    for (int j = 0; j < 16; j++)
        if (t * 16 + j < m) atomicAdd(&hm[d[j] >> 8], 1);
    __syncthreads();
    // shfl-based exclusive scan of 512 counters (2 per thread)
    int v0 = h0[2 * t] + h1[2 * t];
    int v1 = h0[2 * t + 1] + h1[2 * t + 1];
    int sum = v0 + v1;
    int incl = sum;
#pragma unroll
    for (int dd = 1; dd < 64; dd <<= 1) {
        int y = __shfl_up(incl, dd, 64);
        if (lane >= dd) incl += y;
    }
    if (lane == 63) wtot[w] = incl;
    __syncthreads();
    int pre = 0;
#pragma unroll
    for (int ww = 0; ww < 4; ww++) pre += (ww < w) ? wtot[ww] : 0;
    int ex = pre + incl - sum;
    lstart[2 * t] = ex;     lstart[2 * t + 1] = ex + v0;
    lcur[2 * t]   = ex;     lcur[2 * t + 1]   = ex + v0;
    // global range reservation per touched bucket (fixed-capacity regions)
    for (int b = t; b < nbuck; b += 256) {
        int hv = h0[b] + h1[b];
        gbase[b] = hv ? atomicAdd(&gcur8[b * NXC + x], hv) : 0;
    }
    __syncthreads();
    // LDS sort (scatter to dense local ranks)
#pragma unroll
    for (int j = 0; j < 16; j++) {
        if (t * 16 + j < m) {
            int b = d[j] >> 8;
            int p = atomicAdd(&lcur[b], 1);
            packed[p] = ((unsigned)(d[j] & 255) << 24) | (unsigned)sv[j];
            sbkt[p] = (unsigned short)b;
        }
    }
    __syncthreads();
    // coalesced write-out: consecutive local ranks -> consecutive global slots
    for (int idx = t; idx < m; idx += 256) {
        int b = sbkt[idx];
        binned[gbase[b] + (idx - lstart[b])] = packed[idx];
    }
}

// ---------------- pass B: per-(bucket,half) fine sort + cnt/off/dinv + xs ------
// grid = 2*nbuck; block (b,h) handles fine ids [h*128,(h+1)*128): streams all 8
// sub-ranges, keeps its half, writes dense lists into the half's sub-region.
__global__ void k_binB(const unsigned* __restrict__ binned, const int* __restrict__ gcur8,
                       const float* __restrict__ an, const float* __restrict__ pos,
                       int* __restrict__ cnt, int* __restrict__ off,
                       float* __restrict__ dinv, float4* __restrict__ xs,
                       int* __restrict__ eidx, int n, int capx) {
    __shared__ int h[HALF];
    __shared__ int cur[HALF];
    __shared__ int wtot[2];
    int bh = blockIdx.x, t = threadIdx.x;
    int b = bh >> 1, half = bh & 1;
    int cbase = b * NXC;
    int hb = cbase * capx + half * (NXC / 2) * capx;   // half's output base
    if (t < HALF) h[t] = 0;
    __syncthreads();
#pragma unroll
    for (int x = 0; x < NXC; x++) {
        int rs = (cbase + x) * capx, re = gcur8[cbase + x];
        for (int k = rs + t; k < re; k += 256) {
            int f = (int)(binned[k] >> 24);
            if ((f >> 7) == half) atomicAdd(&h[f & (HALF - 1)], 1);
        }
    }
    __syncthreads();
    // shfl exclusive scan of 128 counters (threads 0..127, 2 waves)
    int v = 0, ex = 0;
    if (t < HALF) {
        int lane = t & 63, w = t >> 6;
        v = h[t];
        int incl = v;
#pragma unroll
        for (int dd = 1; dd < 64; dd <<= 1) {
            int y = __shfl_up(incl, dd, 64);
            if (lane >= dd) incl += y;
        }
        if (lane == 63) wtot[w] = incl;
        ex = incl - v;
    }
    __syncthreads();
    if (t < HALF) {
        if (t >= 64) ex += wtot[0];
        cur[t] = ex;
        int node = (b << 8) + half * HALF + t;
        if (node < n) {
            float di = rsqrtf((float)v + 1.0f);   // +1 = self-loop
            cnt[node]  = v;
            off[node]  = hb + ex;
            dinv[node] = di;
            xs[node] = make_float4(an[node] * di, pos[3 * node] * di,
                                   pos[3 * node + 1] * di, pos[3 * node + 2] * di);
        }
    }
    __syncthreads();
#pragma unroll
    for (int x = 0; x < NXC; x++) {
        int rs = (cbase + x) * capx, re = gcur8[cbase + x];
        for (int k = rs + t; k < re; k += 256) {
            unsigned u = binned[k];
            int f = (int)(u >> 24);
            if ((f >> 7) == half) {
                int p = atomicAdd(&cur[f & (HALF - 1)], 1);
                eidx[hb + p] = (int)(u & 0xFFFFFF);
            }
        }
    }
}

// ---------------- fused layer-1 gather + dense + z projection ------------------
// 2 threads per node: edge loop split by parity, a combined via shfl; dense
// loop redundant (weights wave-uniform -> scalar loads); even thread stores.
__global__ void k_gxz(const float4* __restrict__ xs, const int* __restrict__ eidx,
                      const int* __restrict__ off, const int* __restrict__ cnt,
                      const float* __restrict__ dinv, const float* __restrict__ W1,
                      const float* __restrict__ b1, const float* __restrict__ C,
                      uint4* __restrict__ z, int n) {
    int tid = blockIdx.x * 256 + threadIdx.x;
    int i = tid >> 1;
    int par = tid & 1;
    if (i >= n) return;
    float4 a = par ? make_float4(0.f, 0.f, 0.f, 0.f) : xs[i];   // self-loop once
    int o = off[i], c = cnt[i];
    int k = par;
    for (; k + 6 < c; k += 8) {
        int i0 = eidx[o + k],     i1 = eidx[o + k + 2];
        int i2 = eidx[o + k + 4], i3 = eidx[o + k + 6];
        float4 v0 = xs[i0], v1 = xs[i1], v2 = xs[i2], v3 = xs[i3];
        a.x += v0.x + v1.x + v2.x + v3.x;
        a.y += v0.y + v1.y + v2.y + v3.y;
        a.z += v0.z + v1.z + v2.z + v3.z;
        a.w += v0.w + v1.w + v2.w + v3.w;
    }
    for (; k < c; k += 2) {
        float4 v0 = xs[eidx[o + k]];
        a.x += v0.x; a.y += v0.y; a.z += v0.z; a.w += v0.w;
    }
    a.x += __shfl_xor(a.x, 1, 64);
    a.y += __shfl_xor(a.y, 1, 64);
    a.z += __shfl_xor(a.z, 1, 64);
    a.w += __shfl_xor(a.w, 1, 64);
    float di = dinv[i];
    float z0 = 0.f, z1 = 0.f, z2 = 0.f, z3 = 0.f,
          z4 = 0.f, z5 = 0.f, z6 = 0.f, z7 = 0.f;
#pragma unroll 4
    for (int kk = 0; kk < HID; kk++) {      // all weight indices wave-uniform
        float x1k = fmaxf(di * (a.x * W1[kk] + a.y * W1[HID + kk] +
                                a.z * W1[2 * HID + kk] + a.w * W1[3 * HID + kk])
                          + b1[kk], 0.0f);
        const float* cr = C + kk * NEXP;
        z0 += x1k * cr[0]; z1 += x1k * cr[1];
        z2 += x1k * cr[2]; z3 += x1k * cr[3];
        z4 += x1k * cr[4]; z5 += x1k * cr[5];
        z6 += x1k * cr[6]; z7 += x1k * cr[7];
    }
    if (par == 0) {
        uint4 outv;
        outv.x = packbf(z0 * di, z1 * di);
        outv.y = packbf(z2 * di, z3 * di);
        outv.z = packbf(z4 * di, z5 * di);
        outv.w = packbf(z6 * di, z7 * di);
        z[i] = outv;
    }
}

// ---------------- fused gather2 + pooling: edge-parallel 16-lane slots ---------
__global__ void k_gz(const uint4* __restrict__ z4, const int* __restrict__ eidx,
                     const int* __restrict__ off, const int* __restrict__ cnt,
                     const float* __restrict__ dinv, const int* __restrict__ batch,
                     float* __restrict__ pool, float* __restrict__ pcnt, int n) {
    int t = threadIdx.x;
    int slot = t >> 4;          // 0..15 within block
    int l = t & 15;             // lane within slot
    int i0 = blockIdx.x * (16 * NPS) + slot * NPS;
    if (i0 >= n) return;
    int i1 = i0 + NPS < n ? i0 + NPS : n;
    int rep = (blockIdx.x + slot) & (NREP - 1);
    float* rp  = pool + (size_t)rep * NGRAPH * NEXP;
    float* rpc = pcnt + (size_t)rep * NGRAPH;
    int Q = l >> 2;

    int curg = -1;
    float r0 = 0.0f, r1 = 0.0f, runlen = 0.0f;
    for (int i = i0; i < i1; i++) {
        float a0 = 0.f, a1 = 0.f, a2 = 0.f, a3 = 0.f,
              a4 = 0.f, a5 = 0.f, a6 = 0.f, a7 = 0.f;
        int o = off[i], c = cnt[i];
        for (int k = l; k < c; k += 16) {
            uint4 zr = z4[eidx[o + k]];
            a0 += bflo(zr.x); a1 += bfhi(zr.x);
            a2 += bflo(zr.y); a3 += bfhi(zr.y);
            a4 += bflo(zr.z); a5 += bfhi(zr.z);
            a6 += bflo(zr.w); a7 += bfhi(zr.w);
        }
        if (l == 0) {                        // self-loop once
            uint4 zr = z4[i];
            a0 += bflo(zr.x); a1 += bfhi(zr.x);
            a2 += bflo(zr.y); a3 += bfhi(zr.y);
            a4 += bflo(zr.z); a5 += bfhi(zr.z);
            a6 += bflo(zr.w); a7 += bfhi(zr.w);
        }
        a0 += __shfl_xor(a0, 8, 64); a1 += __shfl_xor(a1, 8, 64);
        a2 += __shfl_xor(a2, 8, 64); a3 += __shfl_xor(a3, 8, 64);
        a4 += __shfl_xor(a4, 8, 64); a5 += __shfl_xor(a5, 8, 64);
        a6 += __shfl_xor(a6, 8, 64); a7 += __shfl_xor(a7, 8, 64);
        a0 += __shfl_xor(a0, 4, 64); a1 += __shfl_xor(a1, 4, 64);
        a2 += __shfl_xor(a2, 4, 64); a3 += __shfl_xor(a3, 4, 64);
        a4 += __shfl_xor(a4, 4, 64); a5 += __shfl_xor(a5, 4, 64);
        a6 += __shfl_xor(a6, 4, 64); a7 += __shfl_xor(a7, 4, 64);
        float r0v, r1v;
        switch (Q) {
            case 0:  r0v = a0; r1v = a1; break;
            case 1:  r0v = a2; r1v = a3; break;
            case 2:  r0v = a4; r1v = a5; break;
            default: r0v = a6; r1v = a7; break;
        }
        r0v += __shfl_xor(r0v, 1, 64); r1v += __shfl_xor(r1v, 1, 64);
        r0v += __shfl_xor(r0v, 2, 64); r1v += __shfl_xor(r1v, 2, 64);
        float di = dinv[i];
        float v0 = di * r0v, v1 = di * r1v;
        int g = batch[i];
        if (g != curg) {                     // slot-uniform branch
            if (curg >= 0 && (l & 3) == 0) {
                atomicAdd(&rp[curg * NEXP + 2 * Q], r0);
                atomicAdd(&rp[curg * NEXP + 2 * Q + 1], r1);
                if (l == 0) atomicAdd(&rpc[curg], runlen);
            }
            curg = g; r0 = v0; r1 = v1; runlen = 1.0f;
        } else { r0 += v0; r1 += v1; runlen += 1.0f; }
    }
    if (curg >= 0 && (l & 3) == 0) {
        atomicAdd(&rp[curg * NEXP + 2 * Q], r0);
        atomicAdd(&rp[curg * NEXP + 2 * Q + 1], r1);
        if (l == 0) atomicAdd(&rpc[curg], runlen);
    }
}

// ---------------- replica-sum + mean + (blin + b2@Wlin) + log_softmax ----------
__global__ void k_lsm(const float* __restrict__ pool, const float* __restrict__ pcnt,
                      const float* __restrict__ blin, const float* __restrict__ bb2,
                      float* __restrict__ out) {
    int g = threadIdx.x;
    if (g >= NGRAPH) return;
    float p[NEXP];
#pragma unroll
    for (int k = 0; k < NEXP; k++) p[k] = 0.0f;
    float cg = 0.0f;
#pragma unroll
    for (int rr = 0; rr < NREP; rr++) {
#pragma unroll
        for (int k = 0; k < NEXP; k++) p[k] += pool[rr * NGRAPH * NEXP + g * NEXP + k];
        cg += pcnt[rr * NGRAPH + g];
    }
    float inv = 1.0f / fmaxf(cg, 1.0f);
    float v[NEXP], m = -1e30f;
#pragma unroll
    for (int k = 0; k < NEXP; k++) {
        v[k] = p[k] * inv + blin[k] + bb2[k];
        m = fmaxf(m, v[k]);
    }
    float s = 0.0f;
#pragma unroll
    for (int k = 0; k < NEXP; k++) s += expf(v[k] - m);
    float ls = logf(s);
#pragma unroll
    for (int k = 0; k < NEXP; k++) out[g * NEXP + k] = v[k] - m - ls;
}

extern "C" void kernel_launch(void* const* d_in, const int* in_sizes, int n_in,
                              void* d_out, int out_size, void* d_ws, size_t ws_size,
                              hipStream_t stream) {
    const float* an   = (const float*)d_in[0];
    const float* pos  = (const float*)d_in[1];
    const int*   ei   = (const int*)d_in[2];     // [2, E] flat (int32 view)
    const int*   batch= (const int*)d_in[3];
    const float* W1   = (const float*)d_in[4];
    const float* b1   = (const float*)d_in[5];
    const float* W2   = (const float*)d_in[6];
    const float* b2   = (const float*)d_in[7];
    const float* Wlin = (const float*)d_in[8];
    const float* blin = (const float*)d_in[9];
    float* out = (float*)d_out;

    const int n = in_sizes[0];
    const int e = in_sizes[2] / 2;
    const int* src = ei;
    const int* dst = ei + e;

    const int nbuck = (n + 255) >> 8;            // coarse buckets (<= MAXB)
    const int ch    = (e + EPC - 1) / EPC;       // chunks
    const int mreg  = nbuck * NXC;               // fixed-capacity regions
    const int capx  = 2 * (e / (mreg > 0 ? mreg : 1)) + 256;   // ~34 sigma slack

    // workspace layout (16B-aligned buffers first)
    char* p = (char*)d_ws;
    float4* xs    = (float4*)p;       p += sizeof(float4) * (size_t)n;
    uint4*  z     = (uint4*)p;        p += sizeof(uint4) * (size_t)n;   // bf16[8]/node
    float* C      = (float*)p;        p += sizeof(float) * HID * NEXP;
    float* bb2    = (float*)p;        p += sizeof(float) * NEXP;
    float* dinv   = (float*)p;        p += sizeof(float) * (size_t)n;
    float* pool   = (float*)p;        p += sizeof(float) * NREP * NGRAPH * NEXP;
    float* pcnt   = (float*)p;        p += sizeof(float) * NREP * NGRAPH;
    int*   cnt    = (int*)p;          p += sizeof(int) * (size_t)n;
    int*   off    = (int*)p;          p += sizeof(int) * (size_t)n;
    int*   gcur8  = (int*)p;          p += sizeof(int) * (mreg + 8);
    unsigned* binned = (unsigned*)p;  p += sizeof(unsigned) * (size_t)mreg * capx;
    int*   eidx   = (int*)p;          p += sizeof(int) * (size_t)mreg * capx;

    // init (region bases replace hist+cscan) + binning + fine sort
    const int initN = NREP * NGRAPH * NEXP + HID * NEXP + NEXP;
    const int initG = initN > mreg ? initN : mreg;
    k_init0<<<(initG + 255) / 256, 256, 0, stream>>>(pool, pcnt, W2, Wlin, b2, C,
                                                     bb2, gcur8, mreg, capx);
    k_binA<<<ch, 256, 0, stream>>>(src, dst, gcur8, binned, e, nbuck);
    k_binB<<<2 * nbuck, 256, 0, stream>>>(binned, gcur8, an, pos, cnt, off, dinv,
                                          xs, eidx, n, capx);

    // fused layer-1 gather + dense + projection to z (2 threads/node)
    k_gxz<<<(2 * n + 255) / 256, 256, 0, stream>>>(xs, eidx, off, cnt, dinv,
                                                   W1, b1, C, z, n);

    // layer 2 gather in 8-dim z-space + pooling, then log_softmax
    k_gz<<<(n + 16 * NPS - 1) / (16 * NPS), 256, 0, stream>>>(z, eidx, off, cnt, dinv,
                                                              batch, pool, pcnt, n);
    k_lsm<<<1, 64, 0, stream>>>(pool, pcnt, blin, bb2, out);
}

// Round 20
// 176.843 us; speedup vs baseline: 6.4732x; 1.0105x over previous
//
#include <hip/hip_runtime.h>
#include <math.h>

#define HID 128
#define NEXP 8
#define NGRAPH 64
#define EPC 6144       // edges per chunk: run len ~15.7 -> write txns near full-line floor
#define MAXB 512       // max coarse buckets (n <= 131072)
#define NXC 8          // XCD classes (blockIdx&7 heuristic)
#define NREP 8         // pool replicas (atomic-contention spreading)
#define NPS 8          // nodes per 16-lane slot in k_gz
#define HALF 128       // fine ids per k_binB block

__device__ inline unsigned short f2bf(float f) {
    unsigned u = __float_as_uint(f);
    u += 0x7FFF + ((u >> 16) & 1);          // RNE
    return (unsigned short)(u >> 16);
}
__device__ inline unsigned packbf(float lo, float hi) {
    return (unsigned)f2bf(lo) | ((unsigned)f2bf(hi) << 16);
}
__device__ inline float bflo(unsigned u) { return __uint_as_float(u << 16); }
__device__ inline float bfhi(unsigned u) { return __uint_as_float(u & 0xFFFF0000u); }

// ---------------- init: pool/pcnt zero, gcur8 = region bases, C, bb2 -----------
__global__ void k_init0(float* __restrict__ pool, float* __restrict__ pcnt,
                        const float* __restrict__ W2, const float* __restrict__ Wlin,
                        const float* __restrict__ b2, float* __restrict__ C,
                        float* __restrict__ bb2, int* __restrict__ gcur8,
                        int mregions, int capx) {
    int i = blockIdx.x * 256 + threadIdx.x;
    if (i < mregions) gcur8[i] = i * capx;
    if (i < NREP * NGRAPH * NEXP) pool[i] = 0.0f;
    if (i < NREP * NGRAPH) pcnt[i] = 0.0f;
    int ci = i - NREP * NGRAPH * NEXP;
    if (ci >= 0 && ci < HID * NEXP) {        // C[k][j] = sum_m W2[k][m]*Wlin[m][j]
        int k = ci >> 3, j = ci & 7;
        float s = 0.0f;
        for (int m = 0; m < HID; m++) s += W2[k * HID + m] * Wlin[m * NEXP + j];
        C[ci] = s;
    }
    int bi = ci - HID * NEXP;
    if (bi >= 0 && bi < NEXP) {              // bb2[j] = sum_m b2[m]*Wlin[m][j]
        float s = 0.0f;
        for (int m = 0; m < HID; m++) s += b2[m] * Wlin[m * NEXP + bi];
        bb2[bi] = s;
    }
}

// ---------------- pass A: LDS counting-sort binning into fixed regions ---------
// 24 edges/thread via int4 loads; dual LDS histograms; shfl scan; sorted
// write-out in ~15.7-edge runs (write transactions near full-line floor).
__global__ void __launch_bounds__(256) k_binA(
        const int* __restrict__ src, const int* __restrict__ dst,
        int* __restrict__ gcur8, unsigned* __restrict__ binned, int e, int nbuck) {
    __shared__ int h0[MAXB];
    __shared__ int h1[MAXB];
    __shared__ int lstart[MAXB];
    __shared__ int lcur[MAXB];
    __shared__ int gbase[MAXB];
    __shared__ int wtot[4];
    __shared__ unsigned packed[EPC];
    __shared__ unsigned short sbkt[EPC];
    int c = blockIdx.x, t = threadIdx.x;
    int w = t >> 6, lane = t & 63;
    int x = c & (NXC - 1);
    int start = c * EPC;
    int m = e - start < EPC ? e - start : EPC;

    int d[24], sv[24];
    if (m == EPC) {
        const int4* d4 = (const int4*)(dst + start);
        const int4* s4 = (const int4*)(src + start);
#pragma unroll
        for (int q = 0; q < 6; q++) {
            int4 dd4 = d4[6 * t + q];
            int4 ss4 = s4[6 * t + q];
            d[4 * q + 0] = dd4.x; d[4 * q + 1] = dd4.y;
            d[4 * q + 2] = dd4.z; d[4 * q + 3] = dd4.w;
            sv[4 * q + 0] = ss4.x; sv[4 * q + 1] = ss4.y;
            sv[4 * q + 2] = ss4.z; sv[4 * q + 3] = ss4.w;
        }
    } else {
#pragma unroll
        for (int j = 0; j < 24; j++) {
            int idx = t * 24 + j;
            if (idx < m) { d[j] = dst[start + idx]; sv[j] = src[start + idx]; }
        }
    }
    int* hm = (w < 2) ? h0 : h1;
    h0[t] = 0; h0[t + 256] = 0;
    h1[t] = 0; h1[t + 256] = 0;
    __syncthreads();
#pragma unroll
    for (int j = 0; j < 24; j++)
        if (t * 24 + j < m) atomicAdd(&hm[d[j] >> 8], 1);
    __syncthreads();
    // shfl-based exclusive scan of 512 counters (2 per thread)
    int v0 = h0[2 * t] + h1[2 * t];
    int v1 = h0[2 * t + 1] + h1[2 * t + 1];
    int sum = v0 + v1;
    int incl = sum;
#pragma unroll
    for (int dd = 1; dd < 64; dd <<= 1) {
        int y = __shfl_up(incl, dd, 64);
        if (lane >= dd) incl += y;
    }
    if (lane == 63) wtot[w] = incl;
    __syncthreads();
    int pre = 0;
#pragma unroll
    for (int ww = 0; ww < 4; ww++) pre += (ww < w) ? wtot[ww] : 0;
    int ex = pre + incl - sum;
    lstart[2 * t] = ex;     lstart[2 * t + 1] = ex + v0;
    lcur[2 * t]   = ex;     lcur[2 * t + 1]   = ex + v0;
    // global range reservation per touched bucket (fixed-capacity regions)
    for (int b = t; b < nbuck; b += 256) {
        int hv = h0[b] + h1[b];
        gbase[b] = hv ? atomicAdd(&gcur8[b * NXC + x], hv) : 0;
    }
    __syncthreads();
    // LDS sort (scatter to dense local ranks)
#pragma unroll
    for (int j = 0; j < 24; j++) {
        if (t * 24 + j < m) {
            int b = d[j] >> 8;
            int p = atomicAdd(&lcur[b], 1);
            packed[p] = ((unsigned)(d[j] & 255) << 24) | (unsigned)sv[j];
            sbkt[p] = (unsigned short)b;
        }
    }
    __syncthreads();
    // coalesced write-out: consecutive local ranks -> consecutive global slots
    for (int idx = t; idx < m; idx += 256) {
        int b = sbkt[idx];
        binned[gbase[b] + (idx - lstart[b])] = packed[idx];
    }
}

// ---------------- pass B: per-(bucket,half) fine sort + cnt/off/dinv + xs ------
// grid = 2*nbuck; block (b,h) handles fine ids [h*128,(h+1)*128): streams all 8
// sub-ranges, keeps its half, writes dense lists into the half's sub-region.
__global__ void k_binB(const unsigned* __restrict__ binned, const int* __restrict__ gcur8,
                       const float* __restrict__ an, const float* __restrict__ pos,
                       int* __restrict__ cnt, int* __restrict__ off,
                       float* __restrict__ dinv, float4* __restrict__ xs,
                       int* __restrict__ eidx, int n, int capx) {
    __shared__ int h[HALF];
    __shared__ int cur[HALF];
    __shared__ int wtot[2];
    int bh = blockIdx.x, t = threadIdx.x;
    int b = bh >> 1, half = bh & 1;
    int cbase = b * NXC;
    int hb = cbase * capx + half * (NXC / 2) * capx;   // half's output base
    if (t < HALF) h[t] = 0;
    __syncthreads();
#pragma unroll
    for (int x = 0; x < NXC; x++) {
        int rs = (cbase + x) * capx, re = gcur8[cbase + x];
        for (int k = rs + t; k < re; k += 256) {
            int f = (int)(binned[k] >> 24);
            if ((f >> 7) == half) atomicAdd(&h[f & (HALF - 1)], 1);
        }
    }
    __syncthreads();
    // shfl exclusive scan of 128 counters (threads 0..127, 2 waves)
    int v = 0, ex = 0;
    if (t < HALF) {
        int lane = t & 63, w = t >> 6;
        v = h[t];
        int incl = v;
#pragma unroll
        for (int dd = 1; dd < 64; dd <<= 1) {
            int y = __shfl_up(incl, dd, 64);
            if (lane >= dd) incl += y;
        }
        if (lane == 63) wtot[w] = incl;
        ex = incl - v;
    }
    __syncthreads();
    if (t < HALF) {
        if (t >= 64) ex += wtot[0];
        cur[t] = ex;
        int node = (b << 8) + half * HALF + t;
        if (node < n) {
            float di = rsqrtf((float)v + 1.0f);   // +1 = self-loop
            cnt[node]  = v;
            off[node]  = hb + ex;
            dinv[node] = di;
            xs[node] = make_float4(an[node] * di, pos[3 * node] * di,
                                   pos[3 * node + 1] * di, pos[3 * node + 2] * di);
        }
    }
    __syncthreads();
#pragma unroll
    for (int x = 0; x < NXC; x++) {
        int rs = (cbase + x) * capx, re = gcur8[cbase + x];
        for (int k = rs + t; k < re; k += 256) {
            unsigned u = binned[k];
            int f = (int)(u >> 24);
            if ((f >> 7) == half) {
                int p = atomicAdd(&cur[f & (HALF - 1)], 1);
                eidx[hb + p] = (int)(u & 0xFFFFFF);
            }
        }
    }
}

// ---------------- fused layer-1 gather + dense + z projection ------------------
// 2 threads per node: edge loop split by parity, a combined via shfl; dense
// loop redundant (weights wave-uniform -> scalar loads); even thread stores.
__global__ void k_gxz(const float4* __restrict__ xs, const int* __restrict__ eidx,
                      const int* __restrict__ off, const int* __restrict__ cnt,
                      const float* __restrict__ dinv, const float* __restrict__ W1,
                      const float* __restrict__ b1, const float* __restrict__ C,
                      uint4* __restrict__ z, int n) {
    int tid = blockIdx.x * 256 + threadIdx.x;
    int i = tid >> 1;
    int par = tid & 1;
    if (i >= n) return;
    float4 a = par ? make_float4(0.f, 0.f, 0.f, 0.f) : xs[i];   // self-loop once
    int o = off[i], c = cnt[i];
    int k = par;
    for (; k + 6 < c; k += 8) {
        int i0 = eidx[o + k],     i1 = eidx[o + k + 2];
        int i2 = eidx[o + k + 4], i3 = eidx[o + k + 6];
        float4 v0 = xs[i0], v1 = xs[i1], v2 = xs[i2], v3 = xs[i3];
        a.x += v0.x + v1.x + v2.x + v3.x;
        a.y += v0.y + v1.y + v2.y + v3.y;
        a.z += v0.z + v1.z + v2.z + v3.z;
        a.w += v0.w + v1.w + v2.w + v3.w;
    }
    for (; k < c; k += 2) {
        float4 v0 = xs[eidx[o + k]];
        a.x += v0.x; a.y += v0.y; a.z += v0.z; a.w += v0.w;
    }
    a.x += __shfl_xor(a.x, 1, 64);
    a.y += __shfl_xor(a.y, 1, 64);
    a.z += __shfl_xor(a.z, 1, 64);
    a.w += __shfl_xor(a.w, 1, 64);
    float di = dinv[i];
    float z0 = 0.f, z1 = 0.f, z2 = 0.f, z3 = 0.f,
          z4 = 0.f, z5 = 0.f, z6 = 0.f, z7 = 0.f;
#pragma unroll 4
    for (int kk = 0; kk < HID; kk++) {      // all weight indices wave-uniform
        float x1k = fmaxf(di * (a.x * W1[kk] + a.y * W1[HID + kk] +
                                a.z * W1[2 * HID + kk] + a.w * W1[3 * HID + kk])
                          + b1[kk], 0.0f);
        const float* cr = C + kk * NEXP;
        z0 += x1k * cr[0]; z1 += x1k * cr[1];
        z2 += x1k * cr[2]; z3 += x1k * cr[3];
        z4 += x1k * cr[4]; z5 += x1k * cr[5];
        z6 += x1k * cr[6]; z7 += x1k * cr[7];
    }
    if (par == 0) {
        uint4 outv;
        outv.x = packbf(z0 * di, z1 * di);
        outv.y = packbf(z2 * di, z3 * di);
        outv.z = packbf(z4 * di, z5 * di);
        outv.w = packbf(z6 * di, z7 * di);
        z[i] = outv;
    }
}

// ---------------- fused gather2 + pooling: edge-parallel 16-lane slots ---------
__global__ void k_gz(const uint4* __restrict__ z4, const int* __restrict__ eidx,
                     const int* __restrict__ off, const int* __restrict__ cnt,
                     const float* __restrict__ dinv, const int* __restrict__ batch,
                     float* __restrict__ pool, float* __restrict__ pcnt, int n) {
    int t = threadIdx.x;
    int slot = t >> 4;          // 0..15 within block
    int l = t & 15;             // lane within slot
    int i0 = blockIdx.x * (16 * NPS) + slot * NPS;
    if (i0 >= n) return;
    int i1 = i0 + NPS < n ? i0 + NPS : n;
    int rep = (blockIdx.x + slot) & (NREP - 1);
    float* rp  = pool + (size_t)rep * NGRAPH * NEXP;
    float* rpc = pcnt + (size_t)rep * NGRAPH;
    int Q = l >> 2;

    int curg = -1;
    float r0 = 0.0f, r1 = 0.0f, runlen = 0.0f;
    for (int i = i0; i < i1; i++) {
        float a0 = 0.f, a1 = 0.f, a2 = 0.f, a3 = 0.f,
              a4 = 0.f, a5 = 0.f, a6 = 0.f, a7 = 0.f;
        int o = off[i], c = cnt[i];
        for (int k = l; k < c; k += 16) {
            uint4 zr = z4[eidx[o + k]];
            a0 += bflo(zr.x); a1 += bfhi(zr.x);
            a2 += bflo(zr.y); a3 += bfhi(zr.y);
            a4 += bflo(zr.z); a5 += bfhi(zr.z);
            a6 += bflo(zr.w); a7 += bfhi(zr.w);
        }
        if (l == 0) {                        // self-loop once
            uint4 zr = z4[i];
            a0 += bflo(zr.x); a1 += bfhi(zr.x);
            a2 += bflo(zr.y); a3 += bfhi(zr.y);
            a4 += bflo(zr.z); a5 += bfhi(zr.z);
            a6 += bflo(zr.w); a7 += bfhi(zr.w);
        }
        a0 += __shfl_xor(a0, 8, 64); a1 += __shfl_xor(a1, 8, 64);
        a2 += __shfl_xor(a2, 8, 64); a3 += __shfl_xor(a3, 8, 64);
        a4 += __shfl_xor(a4, 8, 64); a5 += __shfl_xor(a5, 8, 64);
        a6 += __shfl_xor(a6, 8, 64); a7 += __shfl_xor(a7, 8, 64);
        a0 += __shfl_xor(a0, 4, 64); a1 += __shfl_xor(a1, 4, 64);
        a2 += __shfl_xor(a2, 4, 64); a3 += __shfl_xor(a3, 4, 64);
        a4 += __shfl_xor(a4, 4, 64); a5 += __shfl_xor(a5, 4, 64);
        a6 += __shfl_xor(a6, 4, 64); a7 += __shfl_xor(a7, 4, 64);
        float r0v, r1v;
        switch (Q) {
            case 0:  r0v = a0; r1v = a1; break;
            case 1:  r0v = a2; r1v = a3; break;
            case 2:  r0v = a4; r1v = a5; break;
            default: r0v = a6; r1v = a7; break;
        }
        r0v += __shfl_xor(r0v, 1, 64); r1v += __shfl_xor(r1v, 1, 64);
        r0v += __shfl_xor(r0v, 2, 64); r1v += __shfl_xor(r1v, 2, 64);
        float di = dinv[i];
        float v0 = di * r0v, v1 = di * r1v;
        int g = batch[i];
        if (g != curg) {                     // slot-uniform branch
            if (curg >= 0 && (l & 3) == 0) {
                atomicAdd(&rp[curg * NEXP + 2 * Q], r0);
                atomicAdd(&rp[curg * NEXP + 2 * Q + 1], r1);
                if (l == 0) atomicAdd(&rpc[curg], runlen);
            }
            curg = g; r0 = v0; r1 = v1; runlen = 1.0f;
        } else { r0 += v0; r1 += v1; runlen += 1.0f; }
    }
    if (curg >= 0 && (l & 3) == 0) {
        atomicAdd(&rp[curg * NEXP + 2 * Q], r0);
        atomicAdd(&rp[curg * NEXP + 2 * Q + 1], r1);
        if (l == 0) atomicAdd(&rpc[curg], runlen);
    }
}

// ---------------- replica-sum + mean + (blin + b2@Wlin) + log_softmax ----------
__global__ void k_lsm(const float* __restrict__ pool, const float* __restrict__ pcnt,
                      const float* __restrict__ blin, const float* __restrict__ bb2,
                      float* __restrict__ out) {
    int g = threadIdx.x;
    if (g >= NGRAPH) return;
    float p[NEXP];
#pragma unroll
    for (int k = 0; k < NEXP; k++) p[k] = 0.0f;
    float cg = 0.0f;
#pragma unroll
    for (int rr = 0; rr < NREP; rr++) {
#pragma unroll
        for (int k = 0; k < NEXP; k++) p[k] += pool[rr * NGRAPH * NEXP + g * NEXP + k];
        cg += pcnt[rr * NGRAPH + g];
    }
    float inv = 1.0f / fmaxf(cg, 1.0f);
    float v[NEXP], m = -1e30f;
#pragma unroll
    for (int k = 0; k < NEXP; k++) {
        v[k] = p[k] * inv + blin[k] + bb2[k];
        m = fmaxf(m, v[k]);
    }
    float s = 0.0f;
#pragma unroll
    for (int k = 0; k < NEXP; k++) s += expf(v[k] - m);
    float ls = logf(s);
#pragma unroll
    for (int k = 0; k < NEXP; k++) out[g * NEXP + k] = v[k] - m - ls;
}

extern "C" void kernel_launch(void* const* d_in, const int* in_sizes, int n_in,
                              void* d_out, int out_size, void* d_ws, size_t ws_size,
                              hipStream_t stream) {
    const float* an   = (const float*)d_in[0];
    const float* pos  = (const float*)d_in[1];
    const int*   ei   = (const int*)d_in[2];     // [2, E] flat (int32 view)
    const int*   batch= (const int*)d_in[3];
    const float* W1   = (const float*)d_in[4];
    const float* b1   = (const float*)d_in[5];
    const float* W2   = (const float*)d_in[6];
    const float* b2   = (const float*)d_in[7];
    const float* Wlin = (const float*)d_in[8];
    const float* blin = (const float*)d_in[9];
    float* out = (float*)d_out;

    const int n = in_sizes[0];
    const int e = in_sizes[2] / 2;
    const int* src = ei;
    const int* dst = ei + e;

    const int nbuck = (n + 255) >> 8;            // coarse buckets (<= MAXB)
    const int ch    = (e + EPC - 1) / EPC;       // chunks
    const int mreg  = nbuck * NXC;               // fixed-capacity regions
    const int capx  = 2 * (e / (mreg > 0 ? mreg : 1)) + 256;   // ~34 sigma slack

    // workspace layout (16B-aligned buffers first)
    char* p = (char*)d_ws;
    float4* xs    = (float4*)p;       p += sizeof(float4) * (size_t)n;
    uint4*  z     = (uint4*)p;        p += sizeof(uint4) * (size_t)n;   // bf16[8]/node
    float* C      = (float*)p;        p += sizeof(float) * HID * NEXP;
    float* bb2    = (float*)p;        p += sizeof(float) * NEXP;
    float* dinv   = (float*)p;        p += sizeof(float) * (size_t)n;
    float* pool   = (float*)p;        p += sizeof(float) * NREP * NGRAPH * NEXP;
    float* pcnt   = (float*)p;        p += sizeof(float) * NREP * NGRAPH;
    int*   cnt    = (int*)p;          p += sizeof(int) * (size_t)n;
    int*   off    = (int*)p;          p += sizeof(int) * (size_t)n;
    int*   gcur8  = (int*)p;          p += sizeof(int) * (mreg + 8);
    unsigned* binned = (unsigned*)p;  p += sizeof(unsigned) * (size_t)mreg * capx;
    int*   eidx   = (int*)p;          p += sizeof(int) * (size_t)mreg * capx;

    // init (region bases replace hist+cscan) + binning + fine sort
    const int initN = NREP * NGRAPH * NEXP + HID * NEXP + NEXP;
    const int initG = initN > mreg ? initN : mreg;
    k_init0<<<(initG + 255) / 256, 256, 0, stream>>>(pool, pcnt, W2, Wlin, b2, C,
                                                     bb2, gcur8, mreg, capx);
    k_binA<<<ch, 256, 0, stream>>>(src, dst, gcur8, binned, e, nbuck);
    k_binB<<<2 * nbuck, 256, 0, stream>>>(binned, gcur8, an, pos, cnt, off, dinv,
                                          xs, eidx, n, capx);

    // fused layer-1 gather + dense + projection to z (2 threads/node)
    k_gxz<<<(2 * n + 255) / 256, 256, 0, stream>>>(xs, eidx, off, cnt, dinv,
                                                   W1, b1, C, z, n);

    // layer 2 gather in 8-dim z-space + pooling, then log_softmax
    k_gz<<<(n + 16 * NPS - 1) / (16 * NPS), 256, 0, stream>>>(z, eidx, off, cnt, dinv,
                                                              batch, pool, pcnt, n);
    k_lsm<<<1, 64, 0, stream>>>(pool, pcnt, blin, bb2, out);
}